// Round 4
// baseline (626.195 us; speedup 1.0000x reference)
//
#include <hip/hip_runtime.h>
#include <hip/hip_fp16.h>

// PerformerAttention fused pipeline, MI355X (gfx950).
// B=8 N=4096 C=768 H=12 DH=64 M=256, fp32 in/out, fp16 MFMA everywhere.
// Round 9:
//  - kv_fused: K/V LDS staging REMOVED (L2-resident data; Common-mistake #7).
//    K/V fragments loaded global->reg directly; P tile is wave-private ->
//    ZERO barriers in the kernel; LDS 52->36 KB -> 4 blocks/CU free-running.
//  - attn_fused: Q LDS staging removed (direct global->reg fragment loads);
//    the two per-iter barriers remain (cross-wave P tile genuinely needs them).
//  - gemm_qkv / gemm_proj / prep / reduce / ln: unchanged from round-3 config.

#define LOG2E 1.44269504088896340736f

typedef _Float16 half8 __attribute__((ext_vector_type(8)));
typedef _Float16 half4_t __attribute__((ext_vector_type(4)));
typedef _Float16 half2_t __attribute__((ext_vector_type(2)));
typedef float f32x4 __attribute__((ext_vector_type(4)));

#if __has_builtin(__builtin_amdgcn_fdot2)
#define FDOT2(a, b, c) __builtin_amdgcn_fdot2((a), (b), (c), false)
#else
#define FDOT2(a, b, c) \
  ((float)(a)[0] * (float)(b)[0] + ((float)(a)[1] * (float)(b)[1] + (c)))
#endif

static __device__ __forceinline__ half2_t pk2(float a, float b) {
#if __has_builtin(__builtin_amdgcn_cvt_pkrtz)
  return __builtin_bit_cast(half2_t, __builtin_amdgcn_cvt_pkrtz(a, b));
#else
  half2_t r; r[0] = (_Float16)a; r[1] = (_Float16)b; return r;
#endif
}

__device__ __forceinline__ void glds16(const _Float16* g, _Float16* s) {
  __builtin_amdgcn_global_load_lds(
      (const __attribute__((address_space(1))) void*)g,
      (__attribute__((address_space(3))) unsigned int*)s,
      16, 0, 0);
}

// ---------------- merged prep: x cast + LDS-tiled weight transposes + rf cast ----------------

__global__ __launch_bounds__(256)
void prep(const float* __restrict__ x, const float* __restrict__ Wqkv,
          const float* __restrict__ Wproj, const float* __restrict__ rfm,
          _Float16* __restrict__ x_h, _Float16* __restrict__ wqkvT,
          _Float16* __restrict__ wprojT, _Float16* __restrict__ rfh) {
  __shared__ _Float16 T[64][72];
  const int bid = blockIdx.x;
  if (bid < 24576) {  // x: 25165824 = 24576*256*4 exactly
    long i = ((long)bid * 256 + threadIdx.x) * 4;
    float4 v = *(const float4*)(x + i);
    half4_t h;
    h[0] = (_Float16)v.x; h[1] = (_Float16)v.y; h[2] = (_Float16)v.z; h[3] = (_Float16)v.w;
    *(half4_t*)(x_h + i) = h;
    return;
  }
  int tb = bid - 24576;
  if (tb < 576) {
    // 64x64 transpose tile: dst[(c0+n)][r0+k] = src[(r0+k)][c0+n]; both dst rows = 768.
    const float* src; _Float16* dst; int Csrc, r0, c0;
    if (tb < 432) {  // Wqkv [768][2304] -> wqkvT [2304][768]; 12 x 36 tiles
      r0 = (tb / 36) * 64; c0 = (tb % 36) * 64; src = Wqkv; dst = wqkvT; Csrc = 2304;
    } else {         // Wproj [768][768] -> wprojT; 12 x 12 tiles
      int t2 = tb - 432;
      r0 = (t2 / 12) * 64; c0 = (t2 % 12) * 64; src = Wproj; dst = wprojT; Csrc = 768;
    }
    const int ri = threadIdx.x >> 4;        // 0..15 (row quad)
    const int ci = (threadIdx.x & 15) * 4;  // 0..60
#pragma unroll
    for (int rr = 0; rr < 4; ++rr) {
      float4 v = *(const float4*)(src + (long)(r0 + ri * 4 + rr) * Csrc + c0 + ci);
      T[ci + 0][ri * 4 + rr] = (_Float16)v.x;
      T[ci + 1][ri * 4 + rr] = (_Float16)v.y;
      T[ci + 2][ri * 4 + rr] = (_Float16)v.z;
      T[ci + 3][ri * 4 + rr] = (_Float16)v.w;
    }
    __syncthreads();
    const int wi = threadIdx.x >> 3;        // 0..31
    const int wj = (threadIdx.x & 7) * 8;   // 0..56
#pragma unroll
    for (int ww = 0; ww < 2; ++ww) {
      const int row = wi * 2 + ww;
      half8 h = *(const half8*)(&T[row][wj]);
      *(half8*)(dst + (long)(c0 + row) * 768 + r0 + wj) = h;
    }
  } else {
    int idx = (tb - 576) * 256 + threadIdx.x;  // rf: 16384 = 64 blocks
    if (idx < 16384) rfh[idx] = (_Float16)rfm[idx];
  }
}

// ---------------- qkv GEMM: 256x256 tile, BK=64, 4-phase pipelined (round-1 version) --------
// A = wqkvT [2304][768] (weight-out dim m), B = x_h [32768][768] (tokens n).
// Strided wave map: wave w -> (wr=w>>2, wc=w&3); A row(t) = wr*16 + t*32,
// B col(u) = wc*16 + u*64. Quadrants: Q1(A0,B0) Q2(A0,B1) Q3(A1,B1) Q4(A1,B0).
// LDS XOR swizzle: 16B slot s at row r holds global slot s^(r&7) (both sides).

__device__ __forceinline__ void stage_unit(const _Float16* __restrict__ G, int grow0,
                                           int kcol, _Float16* lds, int w, int l) {
  // one half-tile (128 rows x 64 cols fp16 = 16 KB): 2 glds16 per thread.
#pragma unroll
  for (int j = 0; j < 2; ++j) {
    const int ci = w + j * 8;            // wave-chunk 0..15 (1 KiB each)
    const int row = ci * 8 + (l >> 3);   // 0..127 within half
    const int col8 = (l & 7) ^ (row & 7);  // pre-swizzled global source slot
    glds16(G + (long)(grow0 + row) * 768 + kcol + col8 * 8, lds + ci * 512);
  }
}

static __device__ __forceinline__ half8 ldsw(const _Float16* buf, int r, int sl) {
  return *(const half8*)(buf + r * 64 + ((sl ^ (r & 7)) << 3));
}

__global__ __launch_bounds__(512)
void gemm_qkv(const _Float16* __restrict__ W, const _Float16* __restrict__ X,
              _Float16* __restrict__ qh, _Float16* __restrict__ kh,
              _Float16* __restrict__ vT,
              float* __restrict__ nsqLq, float* __restrict__ nsqLk) {
  __shared__ __align__(16) _Float16 As[32768];  // 2 bufs x (256x64)
  __shared__ __align__(16) _Float16 Bs[32768];
  const int tid = threadIdx.x;
  const int w = tid >> 6, l = tid & 63;
  const int lr = l & 15, kg = l >> 4;
  const int wr = w >> 2, wc = w & 3;

  // XCD-chunked swizzle: 1152 blocks = 8 XCDs x 144; 9 m-tiles share an X tile.
  const int bid = blockIdx.x;
  const int wg = (bid & 7) * 144 + (bid >> 3);
  const int m0 = (wg % 9) * 256;   // weight-dim tile (0..2304)
  const int n0 = (wg / 9) * 256;   // token tile (0..32768)

  // ---- prologue: kt0 {Ah0,Bh0,Bh1,Ah1} + kt1 {Ah0,Bh0,Bh1} (7 units, 14 loads)
  stage_unit(W, m0,       0,  As,         w, l);
  stage_unit(X, n0,       0,  Bs,         w, l);
  stage_unit(X, n0 + 128, 0,  Bs + 8192,  w, l);
  stage_unit(W, m0 + 128, 0,  As + 8192,  w, l);
  stage_unit(W, m0,       64, As + 16384, w, l);
  stage_unit(X, n0,       64, Bs + 16384, w, l);
  stage_unit(X, n0 + 128, 64, Bs + 24576, w, l);
  asm volatile("s_waitcnt vmcnt(6)" ::: "memory");  // kt0 landed (3 units out)
  __builtin_amdgcn_s_barrier();

  f32x4 acc[8][4];
#pragma unroll
  for (int t = 0; t < 8; ++t)
#pragma unroll
    for (int u = 0; u < 4; ++u) acc[t][u] = (f32x4){0.f, 0.f, 0.f, 0.f};

  for (int kt = 0; kt < 12; ++kt) {
    const int c = kt & 1, o = c ^ 1;
    const _Float16* Ac = As + c * 16384;
    const _Float16* Bc = Bs + c * 16384;
    half8 aR[4][2], bR0[2][2], bR1[2][2];

    // ---- P1: quadrant (th=0, uh=0); reads A-h0 (8) + B-h0 (4, kept to P4)
#pragma unroll
    for (int i = 0; i < 4; ++i) {
      const int r = wr * 16 + i * 32 + lr;
      aR[i][0] = ldsw(Ac, r, kg);
      aR[i][1] = ldsw(Ac, r, 4 + kg);
    }
#pragma unroll
    for (int j = 0; j < 2; ++j) {
      const int r = wc * 16 + j * 64 + lr;
      bR0[j][0] = ldsw(Bc, r, kg);
      bR0[j][1] = ldsw(Bc, r, 4 + kg);
    }
    if (kt + 1 < 12)  // Ah1(kt+1) -> buf o (region last read kt-1 P3)
      stage_unit(W, m0 + 128, (kt + 1) * 64, As + o * 16384 + 8192, w, l);
    __builtin_amdgcn_s_barrier();
    __builtin_amdgcn_s_setprio(1);
#pragma unroll
    for (int ks = 0; ks < 2; ++ks)
#pragma unroll
      for (int i = 0; i < 4; ++i)
#pragma unroll
        for (int j = 0; j < 2; ++j)
          acc[i][j] = __builtin_amdgcn_mfma_f32_16x16x32_f16(aR[i][ks], bR0[j][ks],
                                                             acc[i][j], 0, 0, 0);
    __builtin_amdgcn_s_setprio(0);
    __builtin_amdgcn_s_barrier();

    // ---- P2: (th=0, uh=1); reads B-h1 (4)
#pragma unroll
    for (int j = 0; j < 2; ++j) {
      const int r = 128 + wc * 16 + j * 64 + lr;
      bR1[j][0] = ldsw(Bc, r, kg);
      bR1[j][1] = ldsw(Bc, r, 4 + kg);
    }
    if (kt + 2 < 12)  // Ah0(kt+2) -> buf c (A-h0 last read P1)
      stage_unit(W, m0, (kt + 2) * 64, As + c * 16384, w, l);
    __builtin_amdgcn_s_barrier();
    __builtin_amdgcn_s_setprio(1);
#pragma unroll
    for (int ks = 0; ks < 2; ++ks)
#pragma unroll
      for (int i = 0; i < 4; ++i)
#pragma unroll
        for (int j = 0; j < 2; ++j)
          acc[i][2 + j] = __builtin_amdgcn_mfma_f32_16x16x32_f16(aR[i][ks], bR1[j][ks],
                                                                 acc[i][2 + j], 0, 0, 0);
    __builtin_amdgcn_s_setprio(0);
    __builtin_amdgcn_s_barrier();

    // ---- P3: (th=1, uh=1); reads A-h1 (8)
#pragma unroll
    for (int i = 0; i < 4; ++i) {
      const int r = 128 + wr * 16 + i * 32 + lr;
      aR[i][0] = ldsw(Ac, r, kg);
      aR[i][1] = ldsw(Ac, r, 4 + kg);
    }
    if (kt + 2 < 12)  // Bh0(kt+2) -> buf c (B-h0 LDS last read P1)
      stage_unit(X, n0, (kt + 2) * 64, Bs + c * 16384, w, l);
    __builtin_amdgcn_s_barrier();
    __builtin_amdgcn_s_setprio(1);
#pragma unroll
    for (int ks = 0; ks < 2; ++ks)
#pragma unroll
      for (int i = 0; i < 4; ++i)
#pragma unroll
        for (int j = 0; j < 2; ++j)
          acc[4 + i][2 + j] = __builtin_amdgcn_mfma_f32_16x16x32_f16(aR[i][ks], bR1[j][ks],
                                                                     acc[4 + i][2 + j], 0, 0, 0);
    __builtin_amdgcn_s_setprio(0);
    __builtin_amdgcn_s_barrier();

    // ---- P4: (th=1, uh=0); no LDS reads (aR from P3, bR0 from P1)
    if (kt + 2 < 12)  // Bh1(kt+2) -> buf c (B-h1 last read P2)
      stage_unit(X, n0 + 128, (kt + 2) * 64, Bs + c * 16384 + 8192, w, l);
    if (kt < 10)
      asm volatile("s_waitcnt vmcnt(6)" ::: "memory");  // kt+1 landed, 3 units in flight
    else
      asm volatile("s_waitcnt vmcnt(0)" ::: "memory");  // tail drain (guards broke invariant)
    __builtin_amdgcn_s_barrier();
    __builtin_amdgcn_s_setprio(1);
#pragma unroll
    for (int ks = 0; ks < 2; ++ks)
#pragma unroll
      for (int i = 0; i < 4; ++i)
#pragma unroll
        for (int j = 0; j < 2; ++j)
          acc[4 + i][j] = __builtin_amdgcn_mfma_f32_16x16x32_f16(aR[i][ks], bR0[j][ks],
                                                                 acc[4 + i][j], 0, 0, 0);
    __builtin_amdgcn_s_setprio(0);
    __builtin_amdgcn_s_barrier();
  }

  // ---- epilogue. Fragment (t,u): weight row = m0 + wr*16 + t*32 + kg*4 + r,
  // token = n0 + wc*16 + u*64 + lr. head = hbase + (t>>1) (wave-uniform per t),
  // d = wr*16 + (t&1)*32 + kg*4 + r (wave covers 32 of 64 d; partner wave wr^1 rest).
  const int which = (m0 >= 1536) ? 2 : ((m0 >= 768) ? 1 : 0);
  const int hbase = (m0 - which * 768) >> 6;  // 0,4,8
  const int b_ = n0 >> 12;
  const int nb = n0 & 4095;

  if (which < 2) {
    _Float16* dst = which ? kh : qh;
    float* nd = which ? nsqLk : nsqLq;
    float ns[4][4];
#pragma unroll
    for (int a = 0; a < 4; ++a)
#pragma unroll
      for (int b2 = 0; b2 < 4; ++b2) ns[a][b2] = 0.f;
#pragma unroll
    for (int t = 0; t < 8; ++t) {
      const int h = hbase + (t >> 1);
      const int d0 = wr * 16 + (t & 1) * 32 + kg * 4;
#pragma unroll
      for (int u = 0; u < 4; ++u) {
        const int n_ = nb + wc * 16 + u * 64 + lr;
        half2_t h01 = pk2(acc[t][u][0], acc[t][u][1]);
        half2_t h23 = pk2(acc[t][u][2], acc[t][u][3]);
        half4_t p4; p4[0] = h01[0]; p4[1] = h01[1]; p4[2] = h23[0]; p4[3] = h23[1];
        *(half4_t*)(dst + ((long)(b_ * 12 + h) * 4096 + n_) * 64 + d0) = p4;
#pragma unroll
        for (int r = 0; r < 4; ++r) { float f = (float)p4[r]; ns[t >> 1][u] += f * f; }
      }
    }
    // reduce over kg (shfl), then over wave pair (wr) via LDS overlay on dead As.
    float* nsP = (float*)As;  // 2*4*256 floats = 8 KB
#pragma unroll
    for (int h2 = 0; h2 < 4; ++h2)
#pragma unroll
      for (int u = 0; u < 4; ++u) {
        float s = ns[h2][u];
        s += __shfl_xor(s, 16);
        s += __shfl_xor(s, 32);
        if (kg == 0) nsP[wr * 1024 + h2 * 256 + wc * 16 + u * 64 + lr] = s;
      }
    __syncthreads();
#pragma unroll
    for (int e = 0; e < 2; ++e) {
      const int idx = tid + e * 512;           // 1024 = 4 heads x 256 tokens
      const int h2 = idx >> 8, tk = idx & 255;
      const float vsum = nsP[h2 * 256 + tk] + nsP[1024 + h2 * 256 + tk];
      nd[(long)(b_ * 12 + hbase + h2) * 4096 + nb + tk] = 0.5f * vsum * LOG2E + 4.0f;
    }
  } else {
    // vT [bh][d][n]: lanes lr -> consecutive tokens -> 32B segments
#pragma unroll
    for (int t = 0; t < 8; ++t) {
      const int h = hbase + (t >> 1);
      const long hb = (long)(b_ * 12 + h) * 64;
      const int d0 = wr * 16 + (t & 1) * 32 + kg * 4;
#pragma unroll
      for (int u = 0; u < 4; ++u) {
        const int n_ = nb + wc * 16 + u * 64 + lr;
#pragma unroll
        for (int r = 0; r < 4; ++r)
          vT[(hb + d0 + r) * 4096 + n_] = (_Float16)acc[t][u][r];
      }
    }
  }
}

// ---------------- proj GEMM (m97-style): y = attn @ Wproj + bias + x ----------------

__global__ __launch_bounds__(256)
void gemm_proj(const _Float16* __restrict__ A, const _Float16* __restrict__ BT,
               float* __restrict__ Co, const float* __restrict__ bias,
               const float* __restrict__ resid) {
  __shared__ __align__(16) _Float16 As[128 * 32];
  __shared__ __align__(16) _Float16 Bs[128 * 32];
  const int tid = threadIdx.x;
  const int w = tid >> 6, l = tid & 63;
  const int lr = l & 15, kg = l >> 4;
  const int m0 = blockIdx.y * 128;
  const int n0 = blockIdx.x * 128;
  const int wm = (w >> 1) * 64, wn = (w & 1) * 64;

  const _Float16* gA = A + (long)(m0 + w * 32 + (l >> 2)) * 768 + (l & 3) * 8;
  const _Float16* gB = BT + (long)(n0 + w * 32 + (l >> 2)) * 768 + (l & 3) * 8;
  _Float16* sA = As + (w * 32) * 32;
  _Float16* sB = Bs + (w * 32) * 32;

  f32x4 acc[4][4];
#pragma unroll
  for (int t = 0; t < 4; ++t)
#pragma unroll
    for (int u = 0; u < 4; ++u) acc[t][u] = (f32x4){0.f, 0.f, 0.f, 0.f};

  for (int kc = 0; kc < 24; ++kc) {
    __syncthreads();
    glds16(gA, sA);
    glds16(gA + 16 * 768, sA + 16 * 32);
    glds16(gB, sB);
    glds16(gB + 16 * 768, sB + 16 * 32);
    gA += 32; gB += 32;
    __syncthreads();

    half8 af[4], bf[4];
#pragma unroll
    for (int t = 0; t < 4; ++t)
      af[t] = *(const half8*)(As + (wm + t * 16 + lr) * 32 + kg * 8);
#pragma unroll
    for (int u = 0; u < 4; ++u)
      bf[u] = *(const half8*)(Bs + (wn + u * 16 + lr) * 32 + kg * 8);
#pragma unroll
    for (int t = 0; t < 4; ++t)
#pragma unroll
      for (int u = 0; u < 4; ++u)
        acc[t][u] = __builtin_amdgcn_mfma_f32_16x16x32_f16(af[t], bf[u], acc[t][u], 0, 0, 0);
  }

#pragma unroll
  for (int u = 0; u < 4; ++u) {
    const int col = n0 + wn + u * 16 + lr;
    const float bv = bias[col];
#pragma unroll
    for (int t = 0; t < 4; ++t) {
      const int row = m0 + wm + t * 16 + kg * 4;
#pragma unroll
      for (int r = 0; r < 4; ++r) {
        long idx = (long)(row + r) * 768 + col;
        Co[idx] = acc[t][u][r] + bv + resid[idx];
      }
    }
  }
}

// ---------------- fused phi_k -> kv stage: barrier-free, direct K/V frag loads ----------------

__global__ __launch_bounds__(256)
void kv_fused(const _Float16* __restrict__ kh, const _Float16* __restrict__ vT,
              const _Float16* __restrict__ rfh, const float* __restrict__ nsqLk,
              _Float16* __restrict__ kvpart, float* __restrict__ kspart) {
  __shared__ __align__(16) _Float16 P[256 * 72];  // only LDS: wave-private P tile
  const int chunk = blockIdx.x, bh = blockIdx.y;
  const int tid = threadIdx.x, w = tid >> 6, l = tid & 63;
  const int lr = l & 15, kg = l >> 4;
  const long khbase = (long)bh * 4096 * 64;
  const long vtbase = (long)bh * 64 * 4096;
  const half2_t ONES = {(_Float16)1.f, (_Float16)1.f};

  half8 rf[4][2];
#pragma unroll
  for (int u = 0; u < 4; ++u)
#pragma unroll
    for (int ks = 0; ks < 2; ++ks)
      rf[u][ks] = *(const half8*)(rfh + (w * 64 + u * 16 + lr) * 64 + ks * 32 + kg * 8);

  f32x4 kvacc[4][4];
#pragma unroll
  for (int mt = 0; mt < 4; ++mt)
#pragma unroll
    for (int dt = 0; dt < 4; ++dt) kvacc[mt][dt] = (f32x4){0.f, 0.f, 0.f, 0.f};
  float ksacc[4] = {0.f, 0.f, 0.f, 0.f};

  for (int t8 = 0; t8 < 8; ++t8) {
    const int nt = chunk * 512 + t8 * 64;

    // K fragments direct from global (L2-resident; 64B segments)
    half8 af[4][2];
#pragma unroll
    for (int tt = 0; tt < 4; ++tt)
#pragma unroll
      for (int ks = 0; ks < 2; ++ks)
        af[tt][ks] = *(const half8*)(kh + khbase + (long)(nt + tt * 16 + lr) * 64 +
                                     ks * 32 + kg * 8);

    f32x4 sacc[4][4];
#pragma unroll
    for (int tt = 0; tt < 4; ++tt)
#pragma unroll
      for (int u = 0; u < 4; ++u) sacc[tt][u] = (f32x4){0.f, 0.f, 0.f, 0.f};
#pragma unroll
    for (int ks = 0; ks < 2; ++ks)
#pragma unroll
      for (int tt = 0; tt < 4; ++tt)
#pragma unroll
        for (int u = 0; u < 4; ++u)
          sacc[tt][u] = __builtin_amdgcn_mfma_f32_16x16x32_f16(af[tt][ks], rf[u][ks],
                                                               sacc[tt][u], 0, 0, 0);
    float4 nsq4[4];
#pragma unroll
    for (int tt = 0; tt < 4; ++tt)
      nsq4[tt] = *(const float4*)(nsqLk + (long)bh * 4096 + nt + tt * 16 + kg * 4);
#pragma unroll
    for (int tt = 0; tt < 4; ++tt)
#pragma unroll
      for (int u = 0; u < 4; ++u) {
        float e0 = exp2f(sacc[tt][u][0] * LOG2E - nsq4[tt].x);
        float e1 = exp2f(sacc[tt][u][1] * LOG2E - nsq4[tt].y);
        float e2 = exp2f(sacc[tt][u][2] * LOG2E - nsq4[tt].z);
        float e3 = exp2f(sacc[tt][u][3] * LOG2E - nsq4[tt].w);
        half2_t h01 = pk2(e0, e1), h23 = pk2(e2, e3);
        half4_t p4; p4[0] = h01[0]; p4[1] = h01[1]; p4[2] = h23[0]; p4[3] = h23[1];
        *(half4_t*)(P + (w * 64 + u * 16 + lr) * 72 + tt * 16 + kg * 4) = p4;
      }
    // P rows w*64..+64 are wave-private: no barrier anywhere in this kernel.

    // V fragments direct from global (L2-resident; 64B segments)
#pragma unroll
    for (int ks = 0; ks < 2; ++ks) {
      half8 pa[4], bv[4];
#pragma unroll
      for (int mt = 0; mt < 4; ++mt)
        pa[mt] = *(const half8*)(P + (w * 64 + mt * 16 + lr) * 72 + ks * 32 + kg * 8);
#pragma unroll
      for (int dt = 0; dt < 4; ++dt)
        bv[dt] = *(const half8*)(vT + vtbase + (long)(dt * 16 + lr) * 4096 + nt +
                                 ks * 32 + kg * 8);
#pragma unroll
      for (int mt = 0; mt < 4; ++mt)
#pragma unroll
        for (int dt = 0; dt < 4; ++dt)
          kvacc[mt][dt] = __builtin_amdgcn_mfma_f32_16x16x32_f16(pa[mt], bv[dt],
                                                                 kvacc[mt][dt], 0, 0, 0);
#pragma unroll
      for (int mt = 0; mt < 4; ++mt) {
        const half2_t* pp = (const half2_t*)&pa[mt];
#pragma unroll
        for (int p = 0; p < 4; ++p) ksacc[mt] = FDOT2(pp[p], ONES, ksacc[mt]);
      }
    }
  }

#pragma unroll
  for (int mt = 0; mt < 4; ++mt) {
    float v = ksacc[mt];
    v += __shfl_xor(v, 16);
    v += __shfl_xor(v, 32);
    if (l < 16) kspart[((bh * 8 + chunk) << 8) + w * 64 + mt * 16 + l] = v;
  }
#pragma unroll
  for (int mt = 0; mt < 4; ++mt)
#pragma unroll
    for (int dt = 0; dt < 4; ++dt)
#pragma unroll
      for (int r = 0; r < 4; ++r)
        kvpart[(((long)(bh * 8 + chunk) * 256) + w * 64 + mt * 16 + kg * 4 + r) * 64 +
               dt * 16 + lr] = (_Float16)kvacc[mt][dt][r];
}

// ---------------- merged reductions: kv partials + ksum partials ----------------

__global__ __launch_bounds__(256)
void reduce_all(const _Float16* __restrict__ kvpart, const float* __restrict__ kspart,
                _Float16* __restrict__ kvT, _Float16* __restrict__ ksumh) {
  if (blockIdx.x < 6144) {
    long i = (long)blockIdx.x * 256 + threadIdx.x;  // 96*16384
    const int bh = (int)(i >> 14);
    const int rem = (int)(i & 16383);
    const int m = rem >> 6, d = rem & 63;
    float s = 0.f;
#pragma unroll
    for (int c = 0; c < 8; ++c)
      s += (float)kvpart[(((long)bh * 8 + c) * 256 + m) * 64 + d];
    kvT[(long)bh * 16384 + d * 256 + m] = (_Float16)s;
  } else {
    int i = (blockIdx.x - 6144) * 256 + threadIdx.x;  // 96*256
    int bh = i >> 8, m = i & 255;
    float s = 0.f;
#pragma unroll
    for (int c = 0; c < 8; ++c) s += kspart[((bh * 8 + c) << 8) + m];
    ksumh[i] = (_Float16)s;
  }
}

// ---------------- fused phi_q -> out stage: direct Q frag loads ----------------

__global__ __launch_bounds__(256)
void attn_fused(const _Float16* __restrict__ qh, const _Float16* __restrict__ rfh,
                const float* __restrict__ nsqLq, const _Float16* __restrict__ kvT,
                const _Float16* __restrict__ ksumh, _Float16* __restrict__ attn) {
  __shared__ __align__(16) _Float16 KV[64 * 264];
  __shared__ __align__(16) _Float16 KS[256];
  __shared__ __align__(16) _Float16 P[64 * 264];
  __shared__ __align__(16) float NS[64];
  const int chunk = blockIdx.x, bh = blockIdx.y;
  const int b = bh / 12, h = bh % 12;
  const int tid = threadIdx.x, w = tid >> 6, l = tid & 63;
  const int lr = l & 15, kg = l >> 4;

  {
    const int d = tid >> 2, mb = (tid & 3) * 64;
#pragma unroll
    for (int j = 0; j < 8; ++j)
      *(half8*)(KV + d * 264 + mb + j * 8) =
          *(const half8*)(kvT + (long)bh * 16384 + d * 256 + mb + j * 8);
    if (tid < 32) *(half8*)(KS + tid * 8) = *(const half8*)(ksumh + bh * 256 + tid * 8);
  }

  half8 rf[4][2];
#pragma unroll
  for (int mt = 0; mt < 4; ++mt)
#pragma unroll
    for (int ks = 0; ks < 2; ++ks)
      rf[mt][ks] = *(const half8*)(rfh + (w * 64 + mt * 16 + lr) * 64 + ks * 32 + kg * 8);

  for (int t8 = 0; t8 < 4; ++t8) {
    const int nt = chunk * 256 + t8 * 64;
    __syncthreads();  // t8=0: KV/KS visible; t8>0: P(t8-1) readers done (WAR)

    // Q fragments direct from global (L2-resident; 64B segments)
    half8 bq[4][2];
#pragma unroll
    for (int tt = 0; tt < 4; ++tt)
#pragma unroll
      for (int ks = 0; ks < 2; ++ks)
        bq[tt][ks] = *(const half8*)(qh + ((long)bh * 4096 + nt + tt * 16 + lr) * 64 +
                                     ks * 32 + kg * 8);

    f32x4 sacc[4][4];
#pragma unroll
    for (int mt = 0; mt < 4; ++mt)
#pragma unroll
      for (int tt = 0; tt < 4; ++tt) sacc[mt][tt] = (f32x4){0.f, 0.f, 0.f, 0.f};
#pragma unroll
    for (int ks = 0; ks < 2; ++ks)
#pragma unroll
      for (int mt = 0; mt < 4; ++mt)
#pragma unroll
        for (int tt = 0; tt < 4; ++tt)
          sacc[mt][tt] = __builtin_amdgcn_mfma_f32_16x16x32_f16(rf[mt][ks], bq[tt][ks],
                                                                sacc[mt][tt], 0, 0, 0);
    float nsqv[4];
#pragma unroll
    for (int tt = 0; tt < 4; ++tt)
      nsqv[tt] = nsqLq[(long)bh * 4096 + nt + tt * 16 + lr];
#pragma unroll
    for (int mt = 0; mt < 4; ++mt)
#pragma unroll
      for (int tt = 0; tt < 4; ++tt) {
        float e0 = exp2f(sacc[mt][tt][0] * LOG2E - nsqv[tt]);
        float e1 = exp2f(sacc[mt][tt][1] * LOG2E - nsqv[tt]);
        float e2 = exp2f(sacc[mt][tt][2] * LOG2E - nsqv[tt]);
        float e3 = exp2f(sacc[mt][tt][3] * LOG2E - nsqv[tt]);
        half2_t h01 = pk2(e0, e1), h23 = pk2(e2, e3);
        half4_t p4; p4[0] = h01[0]; p4[1] = h01[1]; p4[2] = h23[0]; p4[3] = h23[1];
        *(half4_t*)(P + (tt * 16 + lr) * 264 + w * 64 + mt * 16 + kg * 4) = p4;
      }
    __syncthreads();  // P ready for cross-wave read

    f32x4 oacc[4];
#pragma unroll
    for (int u = 0; u < 4; ++u) oacc[u] = (f32x4){0.f, 0.f, 0.f, 0.f};
    float nacc = 0.f;
#pragma unroll
    for (int ks = 0; ks < 8; ++ks) {
      half8 ap = *(const half8*)(P + (w * 16 + lr) * 264 + ks * 32 + kg * 8);
      half8 kv8 = *(const half8*)(KS + ks * 32 + kg * 8);
      const half2_t* a2 = (const half2_t*)&ap;
      const half2_t* k2 = (const half2_t*)&kv8;
#pragma unroll
      for (int p = 0; p < 4; ++p) nacc = FDOT2(a2[p], k2[p], nacc);
#pragma unroll
      for (int u = 0; u < 4; ++u) {
        half8 bkv = *(const half8*)(KV + (u * 16 + lr) * 264 + ks * 32 + kg * 8);
        oacc[u] = __builtin_amdgcn_mfma_f32_16x16x32_f16(ap, bkv, oacc[u], 0, 0, 0);
      }
    }
    nacc += __shfl_xor(nacc, 16);
    nacc += __shfl_xor(nacc, 32);
    if (l < 16) NS[w * 16 + l] = nacc;
    f32x4 n4 = *(const f32x4*)(NS + w * 16 + kg * 4);
    float inv[4];
#pragma unroll
    for (int r = 0; r < 4; ++r) inv[r] = 1.f / (n4[r] + 1e-6f);
#pragma unroll
    for (int u = 0; u < 4; ++u)
#pragma unroll
      for (int r = 0; r < 4; ++r)
        attn[((long)b * 4096 + nt + w * 16 + kg * 4 + r) * 768 + h * 64 + u * 16 + lr] =
            (_Float16)(oacc[u][r] * inv[r]);
  }
}

// ---------------- LayerNorm: one wave per row of 768 (in-place safe) ----------------

__global__ __launch_bounds__(256)
void ln_kernel(const float* __restrict__ y, const float* __restrict__ gamma,
               const float* __restrict__ beta, float* __restrict__ outp) {
  const int wv = threadIdx.x >> 6, l = threadIdx.x & 63;
  const long row = (long)blockIdx.x * 4 + wv;
  const float* yr = y + row * 768;
  float v[12];
  float s = 0.f;
#pragma unroll
  for (int j = 0; j < 12; ++j) { v[j] = yr[l + j * 64]; s += v[j]; }
#pragma unroll
  for (int off = 32; off; off >>= 1) s += __shfl_xor(s, off);
  const float mu = s * (1.f / 768.f);
  float vs = 0.f;
#pragma unroll
  for (int j = 0; j < 12; ++j) { float d = v[j] - mu; vs += d * d; }
#pragma unroll
  for (int off = 32; off; off >>= 1) vs += __shfl_xor(vs, off);
  const float rstd = rsqrtf(vs * (1.f / 768.f) + 1e-5f);
  float* orp = outp + row * 768;
#pragma unroll
  for (int j = 0; j < 12; ++j)
    orp[l + j * 64] = (v[j] - mu) * rstd * gamma[l + j * 64] + beta[l + j * 64];
}

// ---------------- launch ----------------

extern "C" void kernel_launch(void* const* d_in, const int* in_sizes, int n_in,
                              void* d_out, int out_size, void* d_ws, size_t ws_size,
                              hipStream_t stream) {
  const float* x = (const float*)d_in[0];
  const float* Wqkv = (const float*)d_in[1];
  const float* Wproj = (const float*)d_in[2];
  const float* bproj = (const float*)d_in[3];
  const float* gamma = (const float*)d_in[4];
  const float* beta = (const float*)d_in[5];
  const float* rfm = (const float*)d_in[6];

  char* ws = (char*)d_ws;
  size_t off = 0;
  auto alloc = [&](size_t bytes) -> void* {
    void* p = ws + off;
    off += (bytes + 255) & ~(size_t)255;
    return p;
  };
  // region A (48MiB), time-shared: x_h -> kvpart -> attn
  char* regionA = (char*)alloc(50331648ULL);
  _Float16* x_h = (_Float16*)regionA;
  _Float16* kvpart = (_Float16*)regionA;  // 96*8*256*64*2 = 25165824 B
  _Float16* attn = (_Float16*)regionA;    // 32768*768*2   = 50331648 B

  _Float16* wqkvT = (_Float16*)alloc(1769472ULL * 2);
  _Float16* wprojT = (_Float16*)alloc(589824ULL * 2);
  _Float16* rfh = (_Float16*)alloc(16384ULL * 2);
  _Float16* qh = (_Float16*)alloc(25165824ULL * 2);   // [bh][n][64]
  _Float16* kh = (_Float16*)alloc(25165824ULL * 2);   // [bh][n][64]
  _Float16* vT = (_Float16*)alloc(25165824ULL * 2);   // [bh][64][n]
  float* nsqLq = (float*)alloc(393216ULL * 4);
  float* nsqLk = (float*)alloc(393216ULL * 4);
  float* kspart = (float*)alloc(96ULL * 8 * 256 * 4);
  _Float16* kvT = (_Float16*)alloc(96ULL * 16384 * 2);  // [bh][d][m]
  _Float16* ksumh = (_Float16*)alloc(96ULL * 256 * 2);
  // total ~207 MB

  float* y = (float*)d_out;

  prep<<<25216, 256, 0, stream>>>(x, Wqkv, Wproj, rfm, x_h, wqkvT, wprojT, rfh);
  gemm_qkv<<<1152, 512, 0, stream>>>(wqkvT, x_h, qh, kh, vT, nsqLq, nsqLk);
  kv_fused<<<dim3(8, 96), 256, 0, stream>>>(kh, vT, rfh, nsqLk, kvpart, kspart);
  reduce_all<<<6240, 256, 0, stream>>>(kvpart, kspart, kvT, ksumh);
  attn_fused<<<dim3(16, 96), 256, 0, stream>>>(qh, rfh, nsqLq, kvT, ksumh, attn);
  gemm_proj<<<dim3(6, 256), 256, 0, stream>>>(attn, wprojT, y, bproj, x);
  ln_kernel<<<8192, 256, 0, stream>>>(y, gamma, beta, y);
}

// Round 5
// 580.324 us; speedup vs baseline: 1.0790x; 1.0790x over previous
//
#include <hip/hip_runtime.h>
#include <hip/hip_fp16.h>

// PerformerAttention fused pipeline, MI355X (gfx950).
// B=8 N=4096 C=768 H=12 DH=64 M=256, fp32 in/out, fp16 MFMA everywhere.
// Round 10:
//  - gemm_qkv epilogue rewritten: results staged through the dead 128KB LDS
//    (As+Bs unified) and written with fully-coalesced half8 bursts.
//    Before: q/k = 8B stores @128B stride, vT = 128 scalar 2B stores/thread
//    -> WRITE_SIZE 179MB vs 78MB ideal (partial-line RMW also inflated FETCH).
//    After: [n][m]-swizzled LDS -> 1KB bursts for q/k (+ fused nsq on readout);
//    [m][n]-swizzled LDS -> 512B bursts for vT.
//  - kv_fused/attn_fused/gemm_proj/prep/reduce/ln: unchanged from round 4.

#define LOG2E 1.44269504088896340736f

typedef _Float16 half8 __attribute__((ext_vector_type(8)));
typedef _Float16 half4_t __attribute__((ext_vector_type(4)));
typedef _Float16 half2_t __attribute__((ext_vector_type(2)));
typedef float f32x4 __attribute__((ext_vector_type(4)));

#if __has_builtin(__builtin_amdgcn_fdot2)
#define FDOT2(a, b, c) __builtin_amdgcn_fdot2((a), (b), (c), false)
#else
#define FDOT2(a, b, c) \
  ((float)(a)[0] * (float)(b)[0] + ((float)(a)[1] * (float)(b)[1] + (c)))
#endif

static __device__ __forceinline__ half2_t pk2(float a, float b) {
#if __has_builtin(__builtin_amdgcn_cvt_pkrtz)
  return __builtin_bit_cast(half2_t, __builtin_amdgcn_cvt_pkrtz(a, b));
#else
  half2_t r; r[0] = (_Float16)a; r[1] = (_Float16)b; return r;
#endif
}

__device__ __forceinline__ void glds16(const _Float16* g, _Float16* s) {
  __builtin_amdgcn_global_load_lds(
      (const __attribute__((address_space(1))) void*)g,
      (__attribute__((address_space(3))) unsigned int*)s,
      16, 0, 0);
}

// ---------------- merged prep: x cast + LDS-tiled weight transposes + rf cast ----------------

__global__ __launch_bounds__(256)
void prep(const float* __restrict__ x, const float* __restrict__ Wqkv,
          const float* __restrict__ Wproj, const float* __restrict__ rfm,
          _Float16* __restrict__ x_h, _Float16* __restrict__ wqkvT,
          _Float16* __restrict__ wprojT, _Float16* __restrict__ rfh) {
  __shared__ _Float16 T[64][72];
  const int bid = blockIdx.x;
  if (bid < 24576) {  // x: 25165824 = 24576*256*4 exactly
    long i = ((long)bid * 256 + threadIdx.x) * 4;
    float4 v = *(const float4*)(x + i);
    half4_t h;
    h[0] = (_Float16)v.x; h[1] = (_Float16)v.y; h[2] = (_Float16)v.z; h[3] = (_Float16)v.w;
    *(half4_t*)(x_h + i) = h;
    return;
  }
  int tb = bid - 24576;
  if (tb < 576) {
    // 64x64 transpose tile: dst[(c0+n)][r0+k] = src[(r0+k)][c0+n]; both dst rows = 768.
    const float* src; _Float16* dst; int Csrc, r0, c0;
    if (tb < 432) {  // Wqkv [768][2304] -> wqkvT [2304][768]; 12 x 36 tiles
      r0 = (tb / 36) * 64; c0 = (tb % 36) * 64; src = Wqkv; dst = wqkvT; Csrc = 2304;
    } else {         // Wproj [768][768] -> wprojT; 12 x 12 tiles
      int t2 = tb - 432;
      r0 = (t2 / 12) * 64; c0 = (t2 % 12) * 64; src = Wproj; dst = wprojT; Csrc = 768;
    }
    const int ri = threadIdx.x >> 4;        // 0..15 (row quad)
    const int ci = (threadIdx.x & 15) * 4;  // 0..60
#pragma unroll
    for (int rr = 0; rr < 4; ++rr) {
      float4 v = *(const float4*)(src + (long)(r0 + ri * 4 + rr) * Csrc + c0 + ci);
      T[ci + 0][ri * 4 + rr] = (_Float16)v.x;
      T[ci + 1][ri * 4 + rr] = (_Float16)v.y;
      T[ci + 2][ri * 4 + rr] = (_Float16)v.z;
      T[ci + 3][ri * 4 + rr] = (_Float16)v.w;
    }
    __syncthreads();
    const int wi = threadIdx.x >> 3;        // 0..31
    const int wj = (threadIdx.x & 7) * 8;   // 0..56
#pragma unroll
    for (int ww = 0; ww < 2; ++ww) {
      const int row = wi * 2 + ww;
      half8 h = *(const half8*)(&T[row][wj]);
      *(half8*)(dst + (long)(c0 + row) * 768 + r0 + wj) = h;
    }
  } else {
    int idx = (tb - 576) * 256 + threadIdx.x;  // rf: 16384 = 64 blocks
    if (idx < 16384) rfh[idx] = (_Float16)rfm[idx];
  }
}

// ---------------- qkv GEMM: 256x256 tile, BK=64, 4-phase pipelined ----------------
// A = wqkvT [2304][768] (weight-out dim m), B = x_h [32768][768] (tokens n).
// Strided wave map: wave w -> (wr=w>>2, wc=w&3); A row(t) = wr*16 + t*32,
// B col(u) = wc*16 + u*64. Quadrants: Q1(A0,B0) Q2(A0,B1) Q3(A1,B1) Q4(A1,B0).
// LDS XOR swizzle: 16B slot s at row r holds global slot s^(r&7) (both sides).
// Epilogue: acc staged through the dead 128KB LDS, coalesced half8 global writes.

__device__ __forceinline__ void stage_unit(const _Float16* __restrict__ G, int grow0,
                                           int kcol, _Float16* lds, int w, int l) {
  // one half-tile (128 rows x 64 cols fp16 = 16 KB): 2 glds16 per thread.
#pragma unroll
  for (int j = 0; j < 2; ++j) {
    const int ci = w + j * 8;            // wave-chunk 0..15 (1 KiB each)
    const int row = ci * 8 + (l >> 3);   // 0..127 within half
    const int col8 = (l & 7) ^ (row & 7);  // pre-swizzled global source slot
    glds16(G + (long)(grow0 + row) * 768 + kcol + col8 * 8, lds + ci * 512);
  }
}

static __device__ __forceinline__ half8 ldsw(const _Float16* buf, int r, int sl) {
  return *(const half8*)(buf + r * 64 + ((sl ^ (r & 7)) << 3));
}

__global__ __launch_bounds__(512)
void gemm_qkv(const _Float16* __restrict__ W, const _Float16* __restrict__ X,
              _Float16* __restrict__ qh, _Float16* __restrict__ kh,
              _Float16* __restrict__ vT,
              float* __restrict__ nsqLq, float* __restrict__ nsqLk) {
  __shared__ __align__(16) _Float16 SMEM[65536];  // K-loop: As|Bs; epilogue: 256x256 stage
  _Float16* As = SMEM;
  _Float16* Bs = SMEM + 32768;
  const int tid = threadIdx.x;
  const int w = tid >> 6, l = tid & 63;
  const int lr = l & 15, kg = l >> 4;
  const int wr = w >> 2, wc = w & 3;

  // XCD-chunked swizzle: 1152 blocks = 8 XCDs x 144; 9 m-tiles share an X tile.
  const int bid = blockIdx.x;
  const int wg = (bid & 7) * 144 + (bid >> 3);
  const int m0 = (wg % 9) * 256;   // weight-dim tile (0..2304)
  const int n0 = (wg / 9) * 256;   // token tile (0..32768)

  // ---- prologue: kt0 {Ah0,Bh0,Bh1,Ah1} + kt1 {Ah0,Bh0,Bh1} (7 units, 14 loads)
  stage_unit(W, m0,       0,  As,         w, l);
  stage_unit(X, n0,       0,  Bs,         w, l);
  stage_unit(X, n0 + 128, 0,  Bs + 8192,  w, l);
  stage_unit(W, m0 + 128, 0,  As + 8192,  w, l);
  stage_unit(W, m0,       64, As + 16384, w, l);
  stage_unit(X, n0,       64, Bs + 16384, w, l);
  stage_unit(X, n0 + 128, 64, Bs + 24576, w, l);
  asm volatile("s_waitcnt vmcnt(6)" ::: "memory");  // kt0 landed (3 units out)
  __builtin_amdgcn_s_barrier();

  f32x4 acc[8][4];
#pragma unroll
  for (int t = 0; t < 8; ++t)
#pragma unroll
    for (int u = 0; u < 4; ++u) acc[t][u] = (f32x4){0.f, 0.f, 0.f, 0.f};

  for (int kt = 0; kt < 12; ++kt) {
    const int c = kt & 1, o = c ^ 1;
    const _Float16* Ac = As + c * 16384;
    const _Float16* Bc = Bs + c * 16384;
    half8 aR[4][2], bR0[2][2], bR1[2][2];

    // ---- P1: quadrant (th=0, uh=0); reads A-h0 (8) + B-h0 (4, kept to P4)
#pragma unroll
    for (int i = 0; i < 4; ++i) {
      const int r = wr * 16 + i * 32 + lr;
      aR[i][0] = ldsw(Ac, r, kg);
      aR[i][1] = ldsw(Ac, r, 4 + kg);
    }
#pragma unroll
    for (int j = 0; j < 2; ++j) {
      const int r = wc * 16 + j * 64 + lr;
      bR0[j][0] = ldsw(Bc, r, kg);
      bR0[j][1] = ldsw(Bc, r, 4 + kg);
    }
    if (kt + 1 < 12)  // Ah1(kt+1) -> buf o (region last read kt-1 P3)
      stage_unit(W, m0 + 128, (kt + 1) * 64, As + o * 16384 + 8192, w, l);
    __builtin_amdgcn_s_barrier();
    __builtin_amdgcn_s_setprio(1);
#pragma unroll
    for (int ks = 0; ks < 2; ++ks)
#pragma unroll
      for (int i = 0; i < 4; ++i)
#pragma unroll
        for (int j = 0; j < 2; ++j)
          acc[i][j] = __builtin_amdgcn_mfma_f32_16x16x32_f16(aR[i][ks], bR0[j][ks],
                                                             acc[i][j], 0, 0, 0);
    __builtin_amdgcn_s_setprio(0);
    __builtin_amdgcn_s_barrier();

    // ---- P2: (th=0, uh=1); reads B-h1 (4)
#pragma unroll
    for (int j = 0; j < 2; ++j) {
      const int r = 128 + wc * 16 + j * 64 + lr;
      bR1[j][0] = ldsw(Bc, r, kg);
      bR1[j][1] = ldsw(Bc, r, 4 + kg);
    }
    if (kt + 2 < 12)  // Ah0(kt+2) -> buf c (A-h0 last read P1)
      stage_unit(W, m0, (kt + 2) * 64, As + c * 16384, w, l);
    __builtin_amdgcn_s_barrier();
    __builtin_amdgcn_s_setprio(1);
#pragma unroll
    for (int ks = 0; ks < 2; ++ks)
#pragma unroll
      for (int i = 0; i < 4; ++i)
#pragma unroll
        for (int j = 0; j < 2; ++j)
          acc[i][2 + j] = __builtin_amdgcn_mfma_f32_16x16x32_f16(aR[i][ks], bR1[j][ks],
                                                                 acc[i][2 + j], 0, 0, 0);
    __builtin_amdgcn_s_setprio(0);
    __builtin_amdgcn_s_barrier();

    // ---- P3: (th=1, uh=1); reads A-h1 (8)
#pragma unroll
    for (int i = 0; i < 4; ++i) {
      const int r = 128 + wr * 16 + i * 32 + lr;
      aR[i][0] = ldsw(Ac, r, kg);
      aR[i][1] = ldsw(Ac, r, 4 + kg);
    }
    if (kt + 2 < 12)  // Bh0(kt+2) -> buf c (B-h0 LDS last read P1)
      stage_unit(X, n0, (kt + 2) * 64, Bs + c * 16384, w, l);
    __builtin_amdgcn_s_barrier();
    __builtin_amdgcn_s_setprio(1);
#pragma unroll
    for (int ks = 0; ks < 2; ++ks)
#pragma unroll
      for (int i = 0; i < 4; ++i)
#pragma unroll
        for (int j = 0; j < 2; ++j)
          acc[4 + i][2 + j] = __builtin_amdgcn_mfma_f32_16x16x32_f16(aR[i][ks], bR1[j][ks],
                                                                     acc[4 + i][2 + j], 0, 0, 0);
    __builtin_amdgcn_s_setprio(0);
    __builtin_amdgcn_s_barrier();

    // ---- P4: (th=1, uh=0); no LDS reads (aR from P3, bR0 from P1)
    if (kt + 2 < 12)  // Bh1(kt+2) -> buf c (B-h1 last read P2)
      stage_unit(X, n0 + 128, (kt + 2) * 64, Bs + c * 16384 + 8192, w, l);
    if (kt < 10)
      asm volatile("s_waitcnt vmcnt(6)" ::: "memory");  // kt+1 landed, 3 units in flight
    else
      asm volatile("s_waitcnt vmcnt(0)" ::: "memory");  // tail drain (guards broke invariant)
    __builtin_amdgcn_s_barrier();
    __builtin_amdgcn_s_setprio(1);
#pragma unroll
    for (int ks = 0; ks < 2; ++ks)
#pragma unroll
      for (int i = 0; i < 4; ++i)
#pragma unroll
        for (int j = 0; j < 2; ++j)
          acc[4 + i][j] = __builtin_amdgcn_mfma_f32_16x16x32_f16(aR[i][ks], bR0[j][ks],
                                                                 acc[4 + i][j], 0, 0, 0);
    __builtin_amdgcn_s_setprio(0);
    __builtin_amdgcn_s_barrier();
  }

  // ---- epilogue via LDS stage (SMEM dead after final barrier) ----
  // Fragment (t,u): m_local = wr*16 + t*32 + kg*4 + r, n_local = wc*16 + u*64 + lr.
  const int which = (m0 >= 1536) ? 2 : ((m0 >= 768) ? 1 : 0);
  const int hbase = (m0 - which * 768) >> 6;  // 0,4,8
  const int b_ = n0 >> 12;
  const int nb = n0 & 4095;

  if (which < 2) {
    _Float16* dst = which ? kh : qh;
    float* nd = which ? nsqLk : nsqLq;
    // stage: SMEM[n][m] (row 512B), 16B-slot swizzle phys = (m>>3) ^ (n&7);
    // half4 sits at (m&4)*2 within its slot (m%8 in {0,4}).
#pragma unroll
    for (int t = 0; t < 8; ++t) {
      const int m_ = wr * 16 + t * 32 + kg * 4;
#pragma unroll
      for (int u = 0; u < 4; ++u) {
        const int n_ = wc * 16 + u * 64 + lr;
        half2_t h01 = pk2(acc[t][u][0], acc[t][u][1]);
        half2_t h23 = pk2(acc[t][u][2], acc[t][u][3]);
        half4_t p4; p4[0] = h01[0]; p4[1] = h01[1]; p4[2] = h23[0]; p4[3] = h23[1];
        *(half4_t*)((char*)SMEM + n_ * 512 + (((m_ >> 3) ^ (n_ & 7)) << 4) +
                    (m_ & 4) * 2) = p4;
      }
    }
    __syncthreads();
    // readout: wave w -> head h2 = w>>1; 8 tokens x 128B = 1KB contiguous per instr.
    const int h2 = w >> 1;
    const int jj = l & 7;
    const long bhout = (long)(b_ * 12 + hbase + h2);
#pragma unroll
    for (int i = 0; i < 16; ++i) {
      const int n_ = (w & 1) * 128 + i * 8 + (l >> 3);
      const int phys = (h2 * 8 + jj) ^ (n_ & 7);
      half8 v = *(const half8*)((const char*)SMEM + n_ * 512 + phys * 16);
      *(half8*)(dst + (bhout * 4096 + nb + n_) * 64 + jj * 8) = v;
      float s = 0.f;
#pragma unroll
      for (int e = 0; e < 8; ++e) { float f = (float)v[e]; s += f * f; }
      s += __shfl_xor(s, 1);
      s += __shfl_xor(s, 2);
      s += __shfl_xor(s, 4);
      if (jj == 0) nd[bhout * 4096 + nb + n_] = 0.5f * s * LOG2E + 4.0f;
    }
  } else {
    // stage: SMEM[m][n] (row 512B), 16B-chunk swizzle phys = (n>>3) ^ (m&7).
#pragma unroll
    for (int t = 0; t < 8; ++t) {
#pragma unroll
      for (int u = 0; u < 4; ++u) {
        const int n_ = wc * 16 + u * 64 + lr;
#pragma unroll
        for (int r = 0; r < 4; ++r) {
          const int m_ = wr * 16 + t * 32 + kg * 4 + r;
          *(_Float16*)((char*)SMEM + m_ * 512 + ((((n_ >> 3)) ^ (m_ & 7)) << 4) +
                       (n_ & 7) * 2) = (_Float16)acc[t][u][r];
        }
      }
    }
    __syncthreads();
    // readout: 2 d-rows per instr, 512B contiguous per row.
#pragma unroll
    for (int i = 0; i < 16; ++i) {
      const int m_ = w * 32 + i * 2 + (l >> 5);
      const int c = l & 31;
      half8 v = *(const half8*)((const char*)SMEM + m_ * 512 + ((c ^ (m_ & 7)) << 4));
      const int h2 = m_ >> 6, d = m_ & 63;
      *(half8*)(vT + ((long)(b_ * 12 + hbase + h2) * 64 + d) * 4096 + nb + c * 8) = v;
    }
  }
}

// ---------------- proj GEMM (m97-style): y = attn @ Wproj + bias + x ----------------

__global__ __launch_bounds__(256)
void gemm_proj(const _Float16* __restrict__ A, const _Float16* __restrict__ BT,
               float* __restrict__ Co, const float* __restrict__ bias,
               const float* __restrict__ resid) {
  __shared__ __align__(16) _Float16 As[128 * 32];
  __shared__ __align__(16) _Float16 Bs[128 * 32];
  const int tid = threadIdx.x;
  const int w = tid >> 6, l = tid & 63;
  const int lr = l & 15, kg = l >> 4;
  const int m0 = blockIdx.y * 128;
  const int n0 = blockIdx.x * 128;
  const int wm = (w >> 1) * 64, wn = (w & 1) * 64;

  const _Float16* gA = A + (long)(m0 + w * 32 + (l >> 2)) * 768 + (l & 3) * 8;
  const _Float16* gB = BT + (long)(n0 + w * 32 + (l >> 2)) * 768 + (l & 3) * 8;
  _Float16* sA = As + (w * 32) * 32;
  _Float16* sB = Bs + (w * 32) * 32;

  f32x4 acc[4][4];
#pragma unroll
  for (int t = 0; t < 4; ++t)
#pragma unroll
    for (int u = 0; u < 4; ++u) acc[t][u] = (f32x4){0.f, 0.f, 0.f, 0.f};

  for (int kc = 0; kc < 24; ++kc) {
    __syncthreads();
    glds16(gA, sA);
    glds16(gA + 16 * 768, sA + 16 * 32);
    glds16(gB, sB);
    glds16(gB + 16 * 768, sB + 16 * 32);
    gA += 32; gB += 32;
    __syncthreads();

    half8 af[4], bf[4];
#pragma unroll
    for (int t = 0; t < 4; ++t)
      af[t] = *(const half8*)(As + (wm + t * 16 + lr) * 32 + kg * 8);
#pragma unroll
    for (int u = 0; u < 4; ++u)
      bf[u] = *(const half8*)(Bs + (wn + u * 16 + lr) * 32 + kg * 8);
#pragma unroll
    for (int t = 0; t < 4; ++t)
#pragma unroll
      for (int u = 0; u < 4; ++u)
        acc[t][u] = __builtin_amdgcn_mfma_f32_16x16x32_f16(af[t], bf[u], acc[t][u], 0, 0, 0);
  }

#pragma unroll
  for (int u = 0; u < 4; ++u) {
    const int col = n0 + wn + u * 16 + lr;
    const float bv = bias[col];
#pragma unroll
    for (int t = 0; t < 4; ++t) {
      const int row = m0 + wm + t * 16 + kg * 4;
#pragma unroll
      for (int r = 0; r < 4; ++r) {
        long idx = (long)(row + r) * 768 + col;
        Co[idx] = acc[t][u][r] + bv + resid[idx];
      }
    }
  }
}

// ---------------- fused phi_k -> kv stage: barrier-free, direct K/V frag loads ----------------

__global__ __launch_bounds__(256)
void kv_fused(const _Float16* __restrict__ kh, const _Float16* __restrict__ vT,
              const _Float16* __restrict__ rfh, const float* __restrict__ nsqLk,
              _Float16* __restrict__ kvpart, float* __restrict__ kspart) {
  __shared__ __align__(16) _Float16 P[256 * 72];  // only LDS: wave-private P tile
  const int chunk = blockIdx.x, bh = blockIdx.y;
  const int tid = threadIdx.x, w = tid >> 6, l = tid & 63;
  const int lr = l & 15, kg = l >> 4;
  const long khbase = (long)bh * 4096 * 64;
  const long vtbase = (long)bh * 64 * 4096;
  const half2_t ONES = {(_Float16)1.f, (_Float16)1.f};

  half8 rf[4][2];
#pragma unroll
  for (int u = 0; u < 4; ++u)
#pragma unroll
    for (int ks = 0; ks < 2; ++ks)
      rf[u][ks] = *(const half8*)(rfh + (w * 64 + u * 16 + lr) * 64 + ks * 32 + kg * 8);

  f32x4 kvacc[4][4];
#pragma unroll
  for (int mt = 0; mt < 4; ++mt)
#pragma unroll
    for (int dt = 0; dt < 4; ++dt) kvacc[mt][dt] = (f32x4){0.f, 0.f, 0.f, 0.f};
  float ksacc[4] = {0.f, 0.f, 0.f, 0.f};

  for (int t8 = 0; t8 < 8; ++t8) {
    const int nt = chunk * 512 + t8 * 64;

    // K fragments direct from global (L2-resident; 64B segments)
    half8 af[4][2];
#pragma unroll
    for (int tt = 0; tt < 4; ++tt)
#pragma unroll
      for (int ks = 0; ks < 2; ++ks)
        af[tt][ks] = *(const half8*)(kh + khbase + (long)(nt + tt * 16 + lr) * 64 +
                                     ks * 32 + kg * 8);

    f32x4 sacc[4][4];
#pragma unroll
    for (int tt = 0; tt < 4; ++tt)
#pragma unroll
      for (int u = 0; u < 4; ++u) sacc[tt][u] = (f32x4){0.f, 0.f, 0.f, 0.f};
#pragma unroll
    for (int ks = 0; ks < 2; ++ks)
#pragma unroll
      for (int tt = 0; tt < 4; ++tt)
#pragma unroll
        for (int u = 0; u < 4; ++u)
          sacc[tt][u] = __builtin_amdgcn_mfma_f32_16x16x32_f16(af[tt][ks], rf[u][ks],
                                                               sacc[tt][u], 0, 0, 0);
    float4 nsq4[4];
#pragma unroll
    for (int tt = 0; tt < 4; ++tt)
      nsq4[tt] = *(const float4*)(nsqLk + (long)bh * 4096 + nt + tt * 16 + kg * 4);
#pragma unroll
    for (int tt = 0; tt < 4; ++tt)
#pragma unroll
      for (int u = 0; u < 4; ++u) {
        float e0 = exp2f(sacc[tt][u][0] * LOG2E - nsq4[tt].x);
        float e1 = exp2f(sacc[tt][u][1] * LOG2E - nsq4[tt].y);
        float e2 = exp2f(sacc[tt][u][2] * LOG2E - nsq4[tt].z);
        float e3 = exp2f(sacc[tt][u][3] * LOG2E - nsq4[tt].w);
        half2_t h01 = pk2(e0, e1), h23 = pk2(e2, e3);
        half4_t p4; p4[0] = h01[0]; p4[1] = h01[1]; p4[2] = h23[0]; p4[3] = h23[1];
        *(half4_t*)(P + (w * 64 + u * 16 + lr) * 72 + tt * 16 + kg * 4) = p4;
      }
    // P rows w*64..+64 are wave-private: no barrier anywhere in this kernel.

    // V fragments direct from global (L2-resident; 64B segments)
#pragma unroll
    for (int ks = 0; ks < 2; ++ks) {
      half8 pa[4], bv[4];
#pragma unroll
      for (int mt = 0; mt < 4; ++mt)
        pa[mt] = *(const half8*)(P + (w * 64 + mt * 16 + lr) * 72 + ks * 32 + kg * 8);
#pragma unroll
      for (int dt = 0; dt < 4; ++dt)
        bv[dt] = *(const half8*)(vT + vtbase + (long)(dt * 16 + lr) * 4096 + nt +
                                 ks * 32 + kg * 8);
#pragma unroll
      for (int mt = 0; mt < 4; ++mt)
#pragma unroll
        for (int dt = 0; dt < 4; ++dt)
          kvacc[mt][dt] = __builtin_amdgcn_mfma_f32_16x16x32_f16(pa[mt], bv[dt],
                                                                 kvacc[mt][dt], 0, 0, 0);
#pragma unroll
      for (int mt = 0; mt < 4; ++mt) {
        const half2_t* pp = (const half2_t*)&pa[mt];
#pragma unroll
        for (int p = 0; p < 4; ++p) ksacc[mt] = FDOT2(pp[p], ONES, ksacc[mt]);
      }
    }
  }

#pragma unroll
  for (int mt = 0; mt < 4; ++mt) {
    float v = ksacc[mt];
    v += __shfl_xor(v, 16);
    v += __shfl_xor(v, 32);
    if (l < 16) kspart[((bh * 8 + chunk) << 8) + w * 64 + mt * 16 + l] = v;
  }
#pragma unroll
  for (int mt = 0; mt < 4; ++mt)
#pragma unroll
    for (int dt = 0; dt < 4; ++dt)
#pragma unroll
      for (int r = 0; r < 4; ++r)
        kvpart[(((long)(bh * 8 + chunk) * 256) + w * 64 + mt * 16 + kg * 4 + r) * 64 +
               dt * 16 + lr] = (_Float16)kvacc[mt][dt][r];
}

// ---------------- merged reductions: kv partials + ksum partials ----------------

__global__ __launch_bounds__(256)
void reduce_all(const _Float16* __restrict__ kvpart, const float* __restrict__ kspart,
                _Float16* __restrict__ kvT, _Float16* __restrict__ ksumh) {
  if (blockIdx.x < 6144) {
    long i = (long)blockIdx.x * 256 + threadIdx.x;  // 96*16384
    const int bh = (int)(i >> 14);
    const int rem = (int)(i & 16383);
    const int m = rem >> 6, d = rem & 63;
    float s = 0.f;
#pragma unroll
    for (int c = 0; c < 8; ++c)
      s += (float)kvpart[(((long)bh * 8 + c) * 256 + m) * 64 + d];
    kvT[(long)bh * 16384 + d * 256 + m] = (_Float16)s;
  } else {
    int i = (blockIdx.x - 6144) * 256 + threadIdx.x;  // 96*256
    int bh = i >> 8, m = i & 255;
    float s = 0.f;
#pragma unroll
    for (int c = 0; c < 8; ++c) s += kspart[((bh * 8 + c) << 8) + m];
    ksumh[i] = (_Float16)s;
  }
}

// ---------------- fused phi_q -> out stage: direct Q frag loads ----------------

__global__ __launch_bounds__(256)
void attn_fused(const _Float16* __restrict__ qh, const _Float16* __restrict__ rfh,
                const float* __restrict__ nsqLq, const _Float16* __restrict__ kvT,
                const _Float16* __restrict__ ksumh, _Float16* __restrict__ attn) {
  __shared__ __align__(16) _Float16 KV[64 * 264];
  __shared__ __align__(16) _Float16 KS[256];
  __shared__ __align__(16) _Float16 P[64 * 264];
  __shared__ __align__(16) float NS[64];
  const int chunk = blockIdx.x, bh = blockIdx.y;
  const int b = bh / 12, h = bh % 12;
  const int tid = threadIdx.x, w = tid >> 6, l = tid & 63;
  const int lr = l & 15, kg = l >> 4;

  {
    const int d = tid >> 2, mb = (tid & 3) * 64;
#pragma unroll
    for (int j = 0; j < 8; ++j)
      *(half8*)(KV + d * 264 + mb + j * 8) =
          *(const half8*)(kvT + (long)bh * 16384 + d * 256 + mb + j * 8);
    if (tid < 32) *(half8*)(KS + tid * 8) = *(const half8*)(ksumh + bh * 256 + tid * 8);
  }

  half8 rf[4][2];
#pragma unroll
  for (int mt = 0; mt < 4; ++mt)
#pragma unroll
    for (int ks = 0; ks < 2; ++ks)
      rf[mt][ks] = *(const half8*)(rfh + (w * 64 + mt * 16 + lr) * 64 + ks * 32 + kg * 8);

  for (int t8 = 0; t8 < 4; ++t8) {
    const int nt = chunk * 256 + t8 * 64;
    __syncthreads();  // t8=0: KV/KS visible; t8>0: P(t8-1) readers done (WAR)

    // Q fragments direct from global (L2-resident; 64B segments)
    half8 bq[4][2];
#pragma unroll
    for (int tt = 0; tt < 4; ++tt)
#pragma unroll
      for (int ks = 0; ks < 2; ++ks)
        bq[tt][ks] = *(const half8*)(qh + ((long)bh * 4096 + nt + tt * 16 + lr) * 64 +
                                     ks * 32 + kg * 8);

    f32x4 sacc[4][4];
#pragma unroll
    for (int mt = 0; mt < 4; ++mt)
#pragma unroll
      for (int tt = 0; tt < 4; ++tt) sacc[mt][tt] = (f32x4){0.f, 0.f, 0.f, 0.f};
#pragma unroll
    for (int ks = 0; ks < 2; ++ks)
#pragma unroll
      for (int mt = 0; mt < 4; ++mt)
#pragma unroll
        for (int tt = 0; tt < 4; ++tt)
          sacc[mt][tt] = __builtin_amdgcn_mfma_f32_16x16x32_f16(rf[mt][ks], bq[tt][ks],
                                                                sacc[mt][tt], 0, 0, 0);
    float nsqv[4];
#pragma unroll
    for (int tt = 0; tt < 4; ++tt)
      nsqv[tt] = nsqLq[(long)bh * 4096 + nt + tt * 16 + lr];
#pragma unroll
    for (int mt = 0; mt < 4; ++mt)
#pragma unroll
      for (int tt = 0; tt < 4; ++tt) {
        float e0 = exp2f(sacc[mt][tt][0] * LOG2E - nsqv[tt]);
        float e1 = exp2f(sacc[mt][tt][1] * LOG2E - nsqv[tt]);
        float e2 = exp2f(sacc[mt][tt][2] * LOG2E - nsqv[tt]);
        float e3 = exp2f(sacc[mt][tt][3] * LOG2E - nsqv[tt]);
        half2_t h01 = pk2(e0, e1), h23 = pk2(e2, e3);
        half4_t p4; p4[0] = h01[0]; p4[1] = h01[1]; p4[2] = h23[0]; p4[3] = h23[1];
        *(half4_t*)(P + (tt * 16 + lr) * 264 + w * 64 + mt * 16 + kg * 4) = p4;
      }
    __syncthreads();  // P ready for cross-wave read

    f32x4 oacc[4];
#pragma unroll
    for (int u = 0; u < 4; ++u) oacc[u] = (f32x4){0.f, 0.f, 0.f, 0.f};
    float nacc = 0.f;
#pragma unroll
    for (int ks = 0; ks < 8; ++ks) {
      half8 ap = *(const half8*)(P + (w * 16 + lr) * 264 + ks * 32 + kg * 8);
      half8 kv8 = *(const half8*)(KS + ks * 32 + kg * 8);
      const half2_t* a2 = (const half2_t*)&ap;
      const half2_t* k2 = (const half2_t*)&kv8;
#pragma unroll
      for (int p = 0; p < 4; ++p) nacc = FDOT2(a2[p], k2[p], nacc);
#pragma unroll
      for (int u = 0; u < 4; ++u) {
        half8 bkv = *(const half8*)(KV + (u * 16 + lr) * 264 + ks * 32 + kg * 8);
        oacc[u] = __builtin_amdgcn_mfma_f32_16x16x32_f16(ap, bkv, oacc[u], 0, 0, 0);
      }
    }
    nacc += __shfl_xor(nacc, 16);
    nacc += __shfl_xor(nacc, 32);
    if (l < 16) NS[w * 16 + l] = nacc;
    f32x4 n4 = *(const f32x4*)(NS + w * 16 + kg * 4);
    float inv[4];
#pragma unroll
    for (int r = 0; r < 4; ++r) inv[r] = 1.f / (n4[r] + 1e-6f);
#pragma unroll
    for (int u = 0; u < 4; ++u)
#pragma unroll
      for (int r = 0; r < 4; ++r)
        attn[((long)b * 4096 + nt + w * 16 + kg * 4 + r) * 768 + h * 64 + u * 16 + lr] =
            (_Float16)(oacc[u][r] * inv[r]);
  }
}

// ---------------- LayerNorm: one wave per row of 768 (in-place safe) ----------------

__global__ __launch_bounds__(256)
void ln_kernel(const float* __restrict__ y, const float* __restrict__ gamma,
               const float* __restrict__ beta, float* __restrict__ outp) {
  const int wv = threadIdx.x >> 6, l = threadIdx.x & 63;
  const long row = (long)blockIdx.x * 4 + wv;
  const float* yr = y + row * 768;
  float v[12];
  float s = 0.f;
#pragma unroll
  for (int j = 0; j < 12; ++j) { v[j] = yr[l + j * 64]; s += v[j]; }
#pragma unroll
  for (int off = 32; off; off >>= 1) s += __shfl_xor(s, off);
  const float mu = s * (1.f / 768.f);
  float vs = 0.f;
#pragma unroll
  for (int j = 0; j < 12; ++j) { float d = v[j] - mu; vs += d * d; }
#pragma unroll
  for (int off = 32; off; off >>= 1) vs += __shfl_xor(vs, off);
  const float rstd = rsqrtf(vs * (1.f / 768.f) + 1e-5f);
  float* orp = outp + row * 768;
#pragma unroll
  for (int j = 0; j < 12; ++j)
    orp[l + j * 64] = (v[j] - mu) * rstd * gamma[l + j * 64] + beta[l + j * 64];
}

// ---------------- launch ----------------

extern "C" void kernel_launch(void* const* d_in, const int* in_sizes, int n_in,
                              void* d_out, int out_size, void* d_ws, size_t ws_size,
                              hipStream_t stream) {
  const float* x = (const float*)d_in[0];
  const float* Wqkv = (const float*)d_in[1];
  const float* Wproj = (const float*)d_in[2];
  const float* bproj = (const float*)d_in[3];
  const float* gamma = (const float*)d_in[4];
  const float* beta = (const float*)d_in[5];
  const float* rfm = (const float*)d_in[6];

  char* ws = (char*)d_ws;
  size_t off = 0;
  auto alloc = [&](size_t bytes) -> void* {
    void* p = ws + off;
    off += (bytes + 255) & ~(size_t)255;
    return p;
  };
  // region A (48MiB), time-shared: x_h -> kvpart -> attn
  char* regionA = (char*)alloc(50331648ULL);
  _Float16* x_h = (_Float16*)regionA;
  _Float16* kvpart = (_Float16*)regionA;  // 96*8*256*64*2 = 25165824 B
  _Float16* attn = (_Float16*)regionA;    // 32768*768*2   = 50331648 B

  _Float16* wqkvT = (_Float16*)alloc(1769472ULL * 2);
  _Float16* wprojT = (_Float16*)alloc(589824ULL * 2);
  _Float16* rfh = (_Float16*)alloc(16384ULL * 2);
  _Float16* qh = (_Float16*)alloc(25165824ULL * 2);   // [bh][n][64]
  _Float16* kh = (_Float16*)alloc(25165824ULL * 2);   // [bh][n][64]
  _Float16* vT = (_Float16*)alloc(25165824ULL * 2);   // [bh][64][n]
  float* nsqLq = (float*)alloc(393216ULL * 4);
  float* nsqLk = (float*)alloc(393216ULL * 4);
  float* kspart = (float*)alloc(96ULL * 8 * 256 * 4);
  _Float16* kvT = (_Float16*)alloc(96ULL * 16384 * 2);  // [bh][d][m]
  _Float16* ksumh = (_Float16*)alloc(96ULL * 256 * 2);
  // total ~207 MB

  float* y = (float*)d_out;

  prep<<<25216, 256, 0, stream>>>(x, Wqkv, Wproj, rfm, x_h, wqkvT, wprojT, rfh);
  gemm_qkv<<<1152, 512, 0, stream>>>(wqkvT, x_h, qh, kh, vT, nsqLq, nsqLk);
  kv_fused<<<dim3(8, 96), 256, 0, stream>>>(kh, vT, rfh, nsqLk, kvpart, kspart);
  reduce_all<<<6240, 256, 0, stream>>>(kvpart, kspart, kvT, ksumh);
  attn_fused<<<dim3(16, 96), 256, 0, stream>>>(qh, rfh, nsqLq, kvT, ksumh, attn);
  gemm_proj<<<dim3(6, 256), 256, 0, stream>>>(attn, wprojT, y, bproj, x);
  ln_kernel<<<8192, 256, 0, stream>>>(y, gamma, beta, y);
}

// Round 7
// 560.716 us; speedup vs baseline: 1.1168x; 1.0350x over previous
//
#include <hip/hip_runtime.h>
#include <hip/hip_fp16.h>

// PerformerAttention fused pipeline, MI355X (gfx950).
// B=8 N=4096 C=768 H=12 DH=64 M=256, fp32 in/out, fp16 MFMA everywhere.
// Round 12 (= round 11 resubmit; previous bench died on container acquire, not
// a kernel error; design re-audited: LDS 100KB ok, glds16 wave-uniform-base ok,
// swizzle bijective both-sides, uniform barriers, ~200 VGPR @ 8 waves ok):
//  - proj_ln kernel: y = LN(attn @ Wproj + bias + x) fused in one pass.
//    Tile 64 tokens x full 768 cols -> LN block-local; A staged once in LDS
//    (XOR-swizzled, zero K-loop barriers); B direct from L2; per-row stats via
//    shfl_xor + 4KB LDS combine. Kills ln_kernel + y's 200MB round-trip.
//  - gemm_qkv (143us, LDS-staged epilogue) and the rest unchanged from round 5.

#define LOG2E 1.44269504088896340736f

typedef _Float16 half8 __attribute__((ext_vector_type(8)));
typedef _Float16 half4_t __attribute__((ext_vector_type(4)));
typedef _Float16 half2_t __attribute__((ext_vector_type(2)));
typedef float f32x4 __attribute__((ext_vector_type(4)));

#if __has_builtin(__builtin_amdgcn_fdot2)
#define FDOT2(a, b, c) __builtin_amdgcn_fdot2((a), (b), (c), false)
#else
#define FDOT2(a, b, c) \
  ((float)(a)[0] * (float)(b)[0] + ((float)(a)[1] * (float)(b)[1] + (c)))
#endif

static __device__ __forceinline__ half2_t pk2(float a, float b) {
#if __has_builtin(__builtin_amdgcn_cvt_pkrtz)
  return __builtin_bit_cast(half2_t, __builtin_amdgcn_cvt_pkrtz(a, b));
#else
  half2_t r; r[0] = (_Float16)a; r[1] = (_Float16)b; return r;
#endif
}

__device__ __forceinline__ void glds16(const _Float16* g, _Float16* s) {
  __builtin_amdgcn_global_load_lds(
      (const __attribute__((address_space(1))) void*)g,
      (__attribute__((address_space(3))) unsigned int*)s,
      16, 0, 0);
}

// ---------------- merged prep: x cast + LDS-tiled weight transposes + rf cast ----------------

__global__ __launch_bounds__(256)
void prep(const float* __restrict__ x, const float* __restrict__ Wqkv,
          const float* __restrict__ Wproj, const float* __restrict__ rfm,
          _Float16* __restrict__ x_h, _Float16* __restrict__ wqkvT,
          _Float16* __restrict__ wprojT, _Float16* __restrict__ rfh) {
  __shared__ _Float16 T[64][72];
  const int bid = blockIdx.x;
  if (bid < 24576) {  // x: 25165824 = 24576*256*4 exactly
    long i = ((long)bid * 256 + threadIdx.x) * 4;
    float4 v = *(const float4*)(x + i);
    half4_t h;
    h[0] = (_Float16)v.x; h[1] = (_Float16)v.y; h[2] = (_Float16)v.z; h[3] = (_Float16)v.w;
    *(half4_t*)(x_h + i) = h;
    return;
  }
  int tb = bid - 24576;
  if (tb < 576) {
    // 64x64 transpose tile: dst[(c0+n)][r0+k] = src[(r0+k)][c0+n]; both dst rows = 768.
    const float* src; _Float16* dst; int Csrc, r0, c0;
    if (tb < 432) {  // Wqkv [768][2304] -> wqkvT [2304][768]; 12 x 36 tiles
      r0 = (tb / 36) * 64; c0 = (tb % 36) * 64; src = Wqkv; dst = wqkvT; Csrc = 2304;
    } else {         // Wproj [768][768] -> wprojT; 12 x 12 tiles
      int t2 = tb - 432;
      r0 = (t2 / 12) * 64; c0 = (t2 % 12) * 64; src = Wproj; dst = wprojT; Csrc = 768;
    }
    const int ri = threadIdx.x >> 4;        // 0..15 (row quad)
    const int ci = (threadIdx.x & 15) * 4;  // 0..60
#pragma unroll
    for (int rr = 0; rr < 4; ++rr) {
      float4 v = *(const float4*)(src + (long)(r0 + ri * 4 + rr) * Csrc + c0 + ci);
      T[ci + 0][ri * 4 + rr] = (_Float16)v.x;
      T[ci + 1][ri * 4 + rr] = (_Float16)v.y;
      T[ci + 2][ri * 4 + rr] = (_Float16)v.z;
      T[ci + 3][ri * 4 + rr] = (_Float16)v.w;
    }
    __syncthreads();
    const int wi = threadIdx.x >> 3;        // 0..31
    const int wj = (threadIdx.x & 7) * 8;   // 0..56
#pragma unroll
    for (int ww = 0; ww < 2; ++ww) {
      const int row = wi * 2 + ww;
      half8 h = *(const half8*)(&T[row][wj]);
      *(half8*)(dst + (long)(c0 + row) * 768 + r0 + wj) = h;
    }
  } else {
    int idx = (tb - 576) * 256 + threadIdx.x;  // rf: 16384 = 64 blocks
    if (idx < 16384) rfh[idx] = (_Float16)rfm[idx];
  }
}

// ---------------- qkv GEMM: 256x256 tile, BK=64, 4-phase pipelined ----------------
// A = wqkvT [2304][768] (weight-out dim m), B = x_h [32768][768] (tokens n).
// Strided wave map: wave w -> (wr=w>>2, wc=w&3); A row(t) = wr*16 + t*32,
// B col(u) = wc*16 + u*64. Quadrants: Q1(A0,B0) Q2(A0,B1) Q3(A1,B1) Q4(A1,B0).
// LDS XOR swizzle: 16B slot s at row r holds global slot s^(r&7) (both sides).
// Epilogue: acc staged through the dead 128KB LDS, coalesced half8 global writes.

__device__ __forceinline__ void stage_unit(const _Float16* __restrict__ G, int grow0,
                                           int kcol, _Float16* lds, int w, int l) {
  // one half-tile (128 rows x 64 cols fp16 = 16 KB): 2 glds16 per thread.
#pragma unroll
  for (int j = 0; j < 2; ++j) {
    const int ci = w + j * 8;            // wave-chunk 0..15 (1 KiB each)
    const int row = ci * 8 + (l >> 3);   // 0..127 within half
    const int col8 = (l & 7) ^ (row & 7);  // pre-swizzled global source slot
    glds16(G + (long)(grow0 + row) * 768 + kcol + col8 * 8, lds + ci * 512);
  }
}

static __device__ __forceinline__ half8 ldsw(const _Float16* buf, int r, int sl) {
  return *(const half8*)(buf + r * 64 + ((sl ^ (r & 7)) << 3));
}

__global__ __launch_bounds__(512)
void gemm_qkv(const _Float16* __restrict__ W, const _Float16* __restrict__ X,
              _Float16* __restrict__ qh, _Float16* __restrict__ kh,
              _Float16* __restrict__ vT,
              float* __restrict__ nsqLq, float* __restrict__ nsqLk) {
  __shared__ __align__(16) _Float16 SMEM[65536];  // K-loop: As|Bs; epilogue: 256x256 stage
  _Float16* As = SMEM;
  _Float16* Bs = SMEM + 32768;
  const int tid = threadIdx.x;
  const int w = tid >> 6, l = tid & 63;
  const int lr = l & 15, kg = l >> 4;
  const int wr = w >> 2, wc = w & 3;

  // XCD-chunked swizzle: 1152 blocks = 8 XCDs x 144; 9 m-tiles share an X tile.
  const int bid = blockIdx.x;
  const int wg = (bid & 7) * 144 + (bid >> 3);
  const int m0 = (wg % 9) * 256;   // weight-dim tile (0..2304)
  const int n0 = (wg / 9) * 256;   // token tile (0..32768)

  // ---- prologue: kt0 {Ah0,Bh0,Bh1,Ah1} + kt1 {Ah0,Bh0,Bh1} (7 units, 14 loads)
  stage_unit(W, m0,       0,  As,         w, l);
  stage_unit(X, n0,       0,  Bs,         w, l);
  stage_unit(X, n0 + 128, 0,  Bs + 8192,  w, l);
  stage_unit(W, m0 + 128, 0,  As + 8192,  w, l);
  stage_unit(W, m0,       64, As + 16384, w, l);
  stage_unit(X, n0,       64, Bs + 16384, w, l);
  stage_unit(X, n0 + 128, 64, Bs + 24576, w, l);
  asm volatile("s_waitcnt vmcnt(6)" ::: "memory");  // kt0 landed (3 units out)
  __builtin_amdgcn_s_barrier();

  f32x4 acc[8][4];
#pragma unroll
  for (int t = 0; t < 8; ++t)
#pragma unroll
    for (int u = 0; u < 4; ++u) acc[t][u] = (f32x4){0.f, 0.f, 0.f, 0.f};

  for (int kt = 0; kt < 12; ++kt) {
    const int c = kt & 1, o = c ^ 1;
    const _Float16* Ac = As + c * 16384;
    const _Float16* Bc = Bs + c * 16384;
    half8 aR[4][2], bR0[2][2], bR1[2][2];

    // ---- P1: quadrant (th=0, uh=0); reads A-h0 (8) + B-h0 (4, kept to P4)
#pragma unroll
    for (int i = 0; i < 4; ++i) {
      const int r = wr * 16 + i * 32 + lr;
      aR[i][0] = ldsw(Ac, r, kg);
      aR[i][1] = ldsw(Ac, r, 4 + kg);
    }
#pragma unroll
    for (int j = 0; j < 2; ++j) {
      const int r = wc * 16 + j * 64 + lr;
      bR0[j][0] = ldsw(Bc, r, kg);
      bR0[j][1] = ldsw(Bc, r, 4 + kg);
    }
    if (kt + 1 < 12)  // Ah1(kt+1) -> buf o (region last read kt-1 P3)
      stage_unit(W, m0 + 128, (kt + 1) * 64, As + o * 16384 + 8192, w, l);
    __builtin_amdgcn_s_barrier();
    __builtin_amdgcn_s_setprio(1);
#pragma unroll
    for (int ks = 0; ks < 2; ++ks)
#pragma unroll
      for (int i = 0; i < 4; ++i)
#pragma unroll
        for (int j = 0; j < 2; ++j)
          acc[i][j] = __builtin_amdgcn_mfma_f32_16x16x32_f16(aR[i][ks], bR0[j][ks],
                                                             acc[i][j], 0, 0, 0);
    __builtin_amdgcn_s_setprio(0);
    __builtin_amdgcn_s_barrier();

    // ---- P2: (th=0, uh=1); reads B-h1 (4)
#pragma unroll
    for (int j = 0; j < 2; ++j) {
      const int r = 128 + wc * 16 + j * 64 + lr;
      bR1[j][0] = ldsw(Bc, r, kg);
      bR1[j][1] = ldsw(Bc, r, 4 + kg);
    }
    if (kt + 2 < 12)  // Ah0(kt+2) -> buf c (A-h0 last read P1)
      stage_unit(W, m0, (kt + 2) * 64, As + c * 16384, w, l);
    __builtin_amdgcn_s_barrier();
    __builtin_amdgcn_s_setprio(1);
#pragma unroll
    for (int ks = 0; ks < 2; ++ks)
#pragma unroll
      for (int i = 0; i < 4; ++i)
#pragma unroll
        for (int j = 0; j < 2; ++j)
          acc[i][2 + j] = __builtin_amdgcn_mfma_f32_16x16x32_f16(aR[i][ks], bR1[j][ks],
                                                                 acc[i][2 + j], 0, 0, 0);
    __builtin_amdgcn_s_setprio(0);
    __builtin_amdgcn_s_barrier();

    // ---- P3: (th=1, uh=1); reads A-h1 (8)
#pragma unroll
    for (int i = 0; i < 4; ++i) {
      const int r = 128 + wr * 16 + i * 32 + lr;
      aR[i][0] = ldsw(Ac, r, kg);
      aR[i][1] = ldsw(Ac, r, 4 + kg);
    }
    if (kt + 2 < 12)  // Bh0(kt+2) -> buf c (B-h0 LDS last read P1)
      stage_unit(X, n0, (kt + 2) * 64, Bs + c * 16384, w, l);
    __builtin_amdgcn_s_barrier();
    __builtin_amdgcn_s_setprio(1);
#pragma unroll
    for (int ks = 0; ks < 2; ++ks)
#pragma unroll
      for (int i = 0; i < 4; ++i)
#pragma unroll
        for (int j = 0; j < 2; ++j)
          acc[4 + i][2 + j] = __builtin_amdgcn_mfma_f32_16x16x32_f16(aR[i][ks], bR1[j][ks],
                                                                     acc[4 + i][2 + j], 0, 0, 0);
    __builtin_amdgcn_s_setprio(0);
    __builtin_amdgcn_s_barrier();

    // ---- P4: (th=1, uh=0); no LDS reads (aR from P3, bR0 from P1)
    if (kt + 2 < 12)  // Bh1(kt+2) -> buf c (B-h1 last read P2)
      stage_unit(X, n0 + 128, (kt + 2) * 64, Bs + c * 16384 + 8192, w, l);
    if (kt < 10)
      asm volatile("s_waitcnt vmcnt(6)" ::: "memory");  // kt+1 landed, 3 units in flight
    else
      asm volatile("s_waitcnt vmcnt(0)" ::: "memory");  // tail drain (guards broke invariant)
    __builtin_amdgcn_s_barrier();
    __builtin_amdgcn_s_setprio(1);
#pragma unroll
    for (int ks = 0; ks < 2; ++ks)
#pragma unroll
      for (int i = 0; i < 4; ++i)
#pragma unroll
        for (int j = 0; j < 2; ++j)
          acc[4 + i][j] = __builtin_amdgcn_mfma_f32_16x16x32_f16(aR[i][ks], bR0[j][ks],
                                                                 acc[4 + i][j], 0, 0, 0);
    __builtin_amdgcn_s_setprio(0);
    __builtin_amdgcn_s_barrier();
  }

  // ---- epilogue via LDS stage (SMEM dead after final barrier) ----
  // Fragment (t,u): m_local = wr*16 + t*32 + kg*4 + r, n_local = wc*16 + u*64 + lr.
  const int which = (m0 >= 1536) ? 2 : ((m0 >= 768) ? 1 : 0);
  const int hbase = (m0 - which * 768) >> 6;  // 0,4,8
  const int b_ = n0 >> 12;
  const int nb = n0 & 4095;

  if (which < 2) {
    _Float16* dst = which ? kh : qh;
    float* nd = which ? nsqLk : nsqLq;
    // stage: SMEM[n][m] (row 512B), 16B-slot swizzle phys = (m>>3) ^ (n&7);
    // half4 sits at (m&4)*2 within its slot (m%8 in {0,4}).
#pragma unroll
    for (int t = 0; t < 8; ++t) {
      const int m_ = wr * 16 + t * 32 + kg * 4;
#pragma unroll
      for (int u = 0; u < 4; ++u) {
        const int n_ = wc * 16 + u * 64 + lr;
        half2_t h01 = pk2(acc[t][u][0], acc[t][u][1]);
        half2_t h23 = pk2(acc[t][u][2], acc[t][u][3]);
        half4_t p4; p4[0] = h01[0]; p4[1] = h01[1]; p4[2] = h23[0]; p4[3] = h23[1];
        *(half4_t*)((char*)SMEM + n_ * 512 + (((m_ >> 3) ^ (n_ & 7)) << 4) +
                    (m_ & 4) * 2) = p4;
      }
    }
    __syncthreads();
    // readout: wave w -> head h2 = w>>1; 8 tokens x 128B = 1KB contiguous per instr.
    const int h2 = w >> 1;
    const int jj = l & 7;
    const long bhout = (long)(b_ * 12 + hbase + h2);
#pragma unroll
    for (int i = 0; i < 16; ++i) {
      const int n_ = (w & 1) * 128 + i * 8 + (l >> 3);
      const int phys = (h2 * 8 + jj) ^ (n_ & 7);
      half8 v = *(const half8*)((const char*)SMEM + n_ * 512 + phys * 16);
      *(half8*)(dst + (bhout * 4096 + nb + n_) * 64 + jj * 8) = v;
      float s = 0.f;
#pragma unroll
      for (int e = 0; e < 8; ++e) { float f = (float)v[e]; s += f * f; }
      s += __shfl_xor(s, 1);
      s += __shfl_xor(s, 2);
      s += __shfl_xor(s, 4);
      if (jj == 0) nd[bhout * 4096 + nb + n_] = 0.5f * s * LOG2E + 4.0f;
    }
  } else {
    // stage: SMEM[m][n] (row 512B), 16B-chunk swizzle phys = (n>>3) ^ (m&7).
#pragma unroll
    for (int t = 0; t < 8; ++t) {
#pragma unroll
      for (int u = 0; u < 4; ++u) {
        const int n_ = wc * 16 + u * 64 + lr;
#pragma unroll
        for (int r = 0; r < 4; ++r) {
          const int m_ = wr * 16 + t * 32 + kg * 4 + r;
          *(_Float16*)((char*)SMEM + m_ * 512 + ((((n_ >> 3)) ^ (m_ & 7)) << 4) +
                       (n_ & 7) * 2) = (_Float16)acc[t][u][r];
        }
      }
    }
    __syncthreads();
    // readout: 2 d-rows per instr, 512B contiguous per row.
#pragma unroll
    for (int i = 0; i < 16; ++i) {
      const int m_ = w * 32 + i * 2 + (l >> 5);
      const int c = l & 31;
      half8 v = *(const half8*)((const char*)SMEM + m_ * 512 + ((c ^ (m_ & 7)) << 4));
      const int h2 = m_ >> 6, d = m_ & 63;
      *(half8*)(vT + ((long)(b_ * 12 + hbase + h2) * 64 + d) * 4096 + nb + c * 8) = v;
    }
  }
}

// ---------------- fused proj + residual + LayerNorm ----------------
// y = LN(attn @ Wproj + bias + x). Tile 64 tokens x full 768 cols.
// A (attn tile) staged once in LDS (XOR-swizzled); B (wprojT, 1.2MB L2-resident)
// direct global->reg; 8 waves each own a 96-col slice; zero barriers in K-loop.
// LN stats: per-lane partials -> shfl_xor over 16-lane row group -> 4KB LDS
// cross-wave combine -> normalize + write final fp32 output.

__global__ __launch_bounds__(512)
void proj_ln(const _Float16* __restrict__ A, const _Float16* __restrict__ BT,
             const float* __restrict__ bias, const float* __restrict__ xres,
             const float* __restrict__ gamma, const float* __restrict__ beta,
             float* __restrict__ y) {
  __shared__ __align__(16) _Float16 Asm[64 * 768];  // 96 KB
  __shared__ __align__(16) float lnS[64][8];
  __shared__ __align__(16) float lnQ[64][8];
  const int tid = threadIdx.x;
  const int w = tid >> 6, l = tid & 63;
  const int lr = l & 15, kg = l >> 4;
  const int m0 = blockIdx.x * 64;
  const int ncol0 = w * 96;

  // stage A tile (64 x 768 fp16) with pre-swizzled source: phys 16B-slot p of
  // row r holds logical slot p ^ (r&7). 12 issues x 512 threads x 16B = 96 KB.
#pragma unroll
  for (int i = 0; i < 12; ++i) {
    const int sg = i * 512 + tid;    // 0..6143
    const int row = sg / 96;
    const int p = sg - row * 96;
    glds16(A + (long)(m0 + row) * 768 + ((p ^ (row & 7)) << 3), Asm + sg * 8);
  }
  asm volatile("s_waitcnt vmcnt(0)" ::: "memory");
  __builtin_amdgcn_s_barrier();

  f32x4 acc[4][6];
#pragma unroll
  for (int mf = 0; mf < 4; ++mf)
#pragma unroll
    for (int nf = 0; nf < 6; ++nf) acc[mf][nf] = (f32x4){0.f, 0.f, 0.f, 0.f};

#pragma unroll 2
  for (int kc = 0; kc < 12; ++kc) {
    half8 bf[6][2];
#pragma unroll
    for (int nf = 0; nf < 6; ++nf)
#pragma unroll
      for (int ks = 0; ks < 2; ++ks)
        bf[nf][ks] = *(const half8*)(BT + (long)(ncol0 + nf * 16 + lr) * 768 +
                                     kc * 64 + ks * 32 + kg * 8);
    half8 af[4][2];
#pragma unroll
    for (int mf = 0; mf < 4; ++mf) {
      const int r = mf * 16 + lr;
#pragma unroll
      for (int ks = 0; ks < 2; ++ks)
        af[mf][ks] = *(const half8*)(Asm + r * 768 +
                                     (((kc * 8 + ks * 4 + kg) ^ (lr & 7)) << 3));
    }
#pragma unroll
    for (int ks = 0; ks < 2; ++ks)
#pragma unroll
      for (int mf = 0; mf < 4; ++mf)
#pragma unroll
        for (int nf = 0; nf < 6; ++nf)
          acc[mf][nf] = __builtin_amdgcn_mfma_f32_16x16x32_f16(af[mf][ks], bf[nf][ks],
                                                               acc[mf][nf], 0, 0, 0);
  }

  // ---- epilogue: + bias + residual, LN stats, normalize, write ----
  float bv[6], gv[6], betv[6];
#pragma unroll
  for (int nf = 0; nf < 6; ++nf) {
    const int col = ncol0 + nf * 16 + lr;
    bv[nf] = bias[col]; gv[nf] = gamma[col]; betv[nf] = beta[col];
  }
#pragma unroll
  for (int mf = 0; mf < 4; ++mf)
#pragma unroll
    for (int r = 0; r < 4; ++r) {
      const int row = mf * 16 + kg * 4 + r;
#pragma unroll
      for (int nf = 0; nf < 6; ++nf)
        acc[mf][nf][r] += bv[nf] + xres[(long)(m0 + row) * 768 + ncol0 + nf * 16 + lr];
    }
  // per-row partials over this wave's 96 cols
#pragma unroll
  for (int mf = 0; mf < 4; ++mf)
#pragma unroll
    for (int r = 0; r < 4; ++r) {
      float s = 0.f, q = 0.f;
#pragma unroll
      for (int nf = 0; nf < 6; ++nf) {
        const float v = acc[mf][nf][r];
        s += v; q += v * v;
      }
      s += __shfl_xor(s, 1); q += __shfl_xor(q, 1);
      s += __shfl_xor(s, 2); q += __shfl_xor(q, 2);
      s += __shfl_xor(s, 4); q += __shfl_xor(q, 4);
      s += __shfl_xor(s, 8); q += __shfl_xor(q, 8);
      if (lr == 0) {
        const int row = mf * 16 + kg * 4 + r;
        lnS[row][w] = s; lnQ[row][w] = q;
      }
    }
  __syncthreads();
#pragma unroll
  for (int mf = 0; mf < 4; ++mf)
#pragma unroll
    for (int r = 0; r < 4; ++r) {
      const int row = mf * 16 + kg * 4 + r;
      f32x4 s0 = *(const f32x4*)&lnS[row][0];
      f32x4 s1 = *(const f32x4*)&lnS[row][4];
      f32x4 q0 = *(const f32x4*)&lnQ[row][0];
      f32x4 q1 = *(const f32x4*)&lnQ[row][4];
      const float s = s0[0] + s0[1] + s0[2] + s0[3] + s1[0] + s1[1] + s1[2] + s1[3];
      const float q = q0[0] + q0[1] + q0[2] + q0[3] + q1[0] + q1[1] + q1[2] + q1[3];
      const float mu = s * (1.f / 768.f);
      const float var = q * (1.f / 768.f) - mu * mu;
      const float rstd = rsqrtf(var + 1e-5f);
#pragma unroll
      for (int nf = 0; nf < 6; ++nf)
        y[(long)(m0 + row) * 768 + ncol0 + nf * 16 + lr] =
            (acc[mf][nf][r] - mu) * rstd * gv[nf] + betv[nf];
    }
}

// ---------------- fused phi_k -> kv stage: barrier-free, direct K/V frag loads ----------------

__global__ __launch_bounds__(256)
void kv_fused(const _Float16* __restrict__ kh, const _Float16* __restrict__ vT,
              const _Float16* __restrict__ rfh, const float* __restrict__ nsqLk,
              _Float16* __restrict__ kvpart, float* __restrict__ kspart) {
  __shared__ __align__(16) _Float16 P[256 * 72];  // only LDS: wave-private P tile
  const int chunk = blockIdx.x, bh = blockIdx.y;
  const int tid = threadIdx.x, w = tid >> 6, l = tid & 63;
  const int lr = l & 15, kg = l >> 4;
  const long khbase = (long)bh * 4096 * 64;
  const long vtbase = (long)bh * 64 * 4096;
  const half2_t ONES = {(_Float16)1.f, (_Float16)1.f};

  half8 rf[4][2];
#pragma unroll
  for (int u = 0; u < 4; ++u)
#pragma unroll
    for (int ks = 0; ks < 2; ++ks)
      rf[u][ks] = *(const half8*)(rfh + (w * 64 + u * 16 + lr) * 64 + ks * 32 + kg * 8);

  f32x4 kvacc[4][4];
#pragma unroll
  for (int mt = 0; mt < 4; ++mt)
#pragma unroll
    for (int dt = 0; dt < 4; ++dt) kvacc[mt][dt] = (f32x4){0.f, 0.f, 0.f, 0.f};
  float ksacc[4] = {0.f, 0.f, 0.f, 0.f};

  for (int t8 = 0; t8 < 8; ++t8) {
    const int nt = chunk * 512 + t8 * 64;

    // K fragments direct from global (L2-resident; 64B segments)
    half8 af[4][2];
#pragma unroll
    for (int tt = 0; tt < 4; ++tt)
#pragma unroll
      for (int ks = 0; ks < 2; ++ks)
        af[tt][ks] = *(const half8*)(kh + khbase + (long)(nt + tt * 16 + lr) * 64 +
                                     ks * 32 + kg * 8);

    f32x4 sacc[4][4];
#pragma unroll
    for (int tt = 0; tt < 4; ++tt)
#pragma unroll
      for (int u = 0; u < 4; ++u) sacc[tt][u] = (f32x4){0.f, 0.f, 0.f, 0.f};
#pragma unroll
    for (int ks = 0; ks < 2; ++ks)
#pragma unroll
      for (int tt = 0; tt < 4; ++tt)
#pragma unroll
        for (int u = 0; u < 4; ++u)
          sacc[tt][u] = __builtin_amdgcn_mfma_f32_16x16x32_f16(af[tt][ks], rf[u][ks],
                                                               sacc[tt][u], 0, 0, 0);
    float4 nsq4[4];
#pragma unroll
    for (int tt = 0; tt < 4; ++tt)
      nsq4[tt] = *(const float4*)(nsqLk + (long)bh * 4096 + nt + tt * 16 + kg * 4);
#pragma unroll
    for (int tt = 0; tt < 4; ++tt)
#pragma unroll
      for (int u = 0; u < 4; ++u) {
        float e0 = exp2f(sacc[tt][u][0] * LOG2E - nsq4[tt].x);
        float e1 = exp2f(sacc[tt][u][1] * LOG2E - nsq4[tt].y);
        float e2 = exp2f(sacc[tt][u][2] * LOG2E - nsq4[tt].z);
        float e3 = exp2f(sacc[tt][u][3] * LOG2E - nsq4[tt].w);
        half2_t h01 = pk2(e0, e1), h23 = pk2(e2, e3);
        half4_t p4; p4[0] = h01[0]; p4[1] = h01[1]; p4[2] = h23[0]; p4[3] = h23[1];
        *(half4_t*)(P + (w * 64 + u * 16 + lr) * 72 + tt * 16 + kg * 4) = p4;
      }
    // P rows w*64..+64 are wave-private: no barrier anywhere in this kernel.

    // V fragments direct from global (L2-resident; 64B segments)
#pragma unroll
    for (int ks = 0; ks < 2; ++ks) {
      half8 pa[4], bv[4];
#pragma unroll
      for (int mt = 0; mt < 4; ++mt)
        pa[mt] = *(const half8*)(P + (w * 64 + mt * 16 + lr) * 72 + ks * 32 + kg * 8);
#pragma unroll
      for (int dt = 0; dt < 4; ++dt)
        bv[dt] = *(const half8*)(vT + vtbase + (long)(dt * 16 + lr) * 4096 + nt +
                                 ks * 32 + kg * 8);
#pragma unroll
      for (int mt = 0; mt < 4; ++mt)
#pragma unroll
        for (int dt = 0; dt < 4; ++dt)
          kvacc[mt][dt] = __builtin_amdgcn_mfma_f32_16x16x32_f16(pa[mt], bv[dt],
                                                                 kvacc[mt][dt], 0, 0, 0);
#pragma unroll
      for (int mt = 0; mt < 4; ++mt) {
        const half2_t* pp = (const half2_t*)&pa[mt];
#pragma unroll
        for (int p = 0; p < 4; ++p) ksacc[mt] = FDOT2(pp[p], ONES, ksacc[mt]);
      }
    }
  }

#pragma unroll
  for (int mt = 0; mt < 4; ++mt) {
    float v = ksacc[mt];
    v += __shfl_xor(v, 16);
    v += __shfl_xor(v, 32);
    if (l < 16) kspart[((bh * 8 + chunk) << 8) + w * 64 + mt * 16 + l] = v;
  }
#pragma unroll
  for (int mt = 0; mt < 4; ++mt)
#pragma unroll
    for (int dt = 0; dt < 4; ++dt)
#pragma unroll
      for (int r = 0; r < 4; ++r)
        kvpart[(((long)(bh * 8 + chunk) * 256) + w * 64 + mt * 16 + kg * 4 + r) * 64 +
               dt * 16 + lr] = (_Float16)kvacc[mt][dt][r];
}

// ---------------- merged reductions: kv partials + ksum partials ----------------

__global__ __launch_bounds__(256)
void reduce_all(const _Float16* __restrict__ kvpart, const float* __restrict__ kspart,
                _Float16* __restrict__ kvT, _Float16* __restrict__ ksumh) {
  if (blockIdx.x < 6144) {
    long i = (long)blockIdx.x * 256 + threadIdx.x;  // 96*16384
    const int bh = (int)(i >> 14);
    const int rem = (int)(i & 16383);
    const int m = rem >> 6, d = rem & 63;
    float s = 0.f;
#pragma unroll
    for (int c = 0; c < 8; ++c)
      s += (float)kvpart[(((long)bh * 8 + c) * 256 + m) * 64 + d];
    kvT[(long)bh * 16384 + d * 256 + m] = (_Float16)s;
  } else {
    int i = (blockIdx.x - 6144) * 256 + threadIdx.x;  // 96*256
    int bh = i >> 8, m = i & 255;
    float s = 0.f;
#pragma unroll
    for (int c = 0; c < 8; ++c) s += kspart[((bh * 8 + c) << 8) + m];
    ksumh[i] = (_Float16)s;
  }
}

// ---------------- fused phi_q -> out stage: direct Q frag loads ----------------

__global__ __launch_bounds__(256)
void attn_fused(const _Float16* __restrict__ qh, const _Float16* __restrict__ rfh,
                const float* __restrict__ nsqLq, const _Float16* __restrict__ kvT,
                const _Float16* __restrict__ ksumh, _Float16* __restrict__ attn) {
  __shared__ __align__(16) _Float16 KV[64 * 264];
  __shared__ __align__(16) _Float16 KS[256];
  __shared__ __align__(16) _Float16 P[64 * 264];
  __shared__ __align__(16) float NS[64];
  const int chunk = blockIdx.x, bh = blockIdx.y;
  const int b = bh / 12, h = bh % 12;
  const int tid = threadIdx.x, w = tid >> 6, l = tid & 63;
  const int lr = l & 15, kg = l >> 4;

  {
    const int d = tid >> 2, mb = (tid & 3) * 64;
#pragma unroll
    for (int j = 0; j < 8; ++j)
      *(half8*)(KV + d * 264 + mb + j * 8) =
          *(const half8*)(kvT + (long)bh * 16384 + d * 256 + mb + j * 8);
    if (tid < 32) *(half8*)(KS + tid * 8) = *(const half8*)(ksumh + bh * 256 + tid * 8);
  }

  half8 rf[4][2];
#pragma unroll
  for (int mt = 0; mt < 4; ++mt)
#pragma unroll
    for (int ks = 0; ks < 2; ++ks)
      rf[mt][ks] = *(const half8*)(rfh + (w * 64 + mt * 16 + lr) * 64 + ks * 32 + kg * 8);

  for (int t8 = 0; t8 < 4; ++t8) {
    const int nt = chunk * 256 + t8 * 64;
    __syncthreads();  // t8=0: KV/KS visible; t8>0: P(t8-1) readers done (WAR)

    // Q fragments direct from global (L2-resident; 64B segments)
    half8 bq[4][2];
#pragma unroll
    for (int tt = 0; tt < 4; ++tt)
#pragma unroll
      for (int ks = 0; ks < 2; ++ks)
        bq[tt][ks] = *(const half8*)(qh + ((long)bh * 4096 + nt + tt * 16 + lr) * 64 +
                                     ks * 32 + kg * 8);

    f32x4 sacc[4][4];
#pragma unroll
    for (int mt = 0; mt < 4; ++mt)
#pragma unroll
      for (int tt = 0; tt < 4; ++tt) sacc[mt][tt] = (f32x4){0.f, 0.f, 0.f, 0.f};
#pragma unroll
    for (int ks = 0; ks < 2; ++ks)
#pragma unroll
      for (int mt = 0; mt < 4; ++mt)
#pragma unroll
        for (int tt = 0; tt < 4; ++tt)
          sacc[mt][tt] = __builtin_amdgcn_mfma_f32_16x16x32_f16(rf[mt][ks], bq[tt][ks],
                                                                sacc[mt][tt], 0, 0, 0);
    float nsqv[4];
#pragma unroll
    for (int tt = 0; tt < 4; ++tt)
      nsqv[tt] = nsqLq[(long)bh * 4096 + nt + tt * 16 + lr];
#pragma unroll
    for (int mt = 0; mt < 4; ++mt)
#pragma unroll
      for (int tt = 0; tt < 4; ++tt) {
        float e0 = exp2f(sacc[mt][tt][0] * LOG2E - nsqv[tt]);
        float e1 = exp2f(sacc[mt][tt][1] * LOG2E - nsqv[tt]);
        float e2 = exp2f(sacc[mt][tt][2] * LOG2E - nsqv[tt]);
        float e3 = exp2f(sacc[mt][tt][3] * LOG2E - nsqv[tt]);
        half2_t h01 = pk2(e0, e1), h23 = pk2(e2, e3);
        half4_t p4; p4[0] = h01[0]; p4[1] = h01[1]; p4[2] = h23[0]; p4[3] = h23[1];
        *(half4_t*)(P + (tt * 16 + lr) * 264 + w * 64 + mt * 16 + kg * 4) = p4;
      }
    __syncthreads();  // P ready for cross-wave read

    f32x4 oacc[4];
#pragma unroll
    for (int u = 0; u < 4; ++u) oacc[u] = (f32x4){0.f, 0.f, 0.f, 0.f};
    float nacc = 0.f;
#pragma unroll
    for (int ks = 0; ks < 8; ++ks) {
      half8 ap = *(const half8*)(P + (w * 16 + lr) * 264 + ks * 32 + kg * 8);
      half8 kv8 = *(const half8*)(KS + ks * 32 + kg * 8);
      const half2_t* a2 = (const half2_t*)&ap;
      const half2_t* k2 = (const half2_t*)&kv8;
#pragma unroll
      for (int p = 0; p < 4; ++p) nacc = FDOT2(a2[p], k2[p], nacc);
#pragma unroll
      for (int u = 0; u < 4; ++u) {
        half8 bkv = *(const half8*)(KV + (u * 16 + lr) * 264 + ks * 32 + kg * 8);
        oacc[u] = __builtin_amdgcn_mfma_f32_16x16x32_f16(ap, bkv, oacc[u], 0, 0, 0);
      }
    }
    nacc += __shfl_xor(nacc, 16);
    nacc += __shfl_xor(nacc, 32);
    if (l < 16) NS[w * 16 + l] = nacc;
    f32x4 n4 = *(const f32x4*)(NS + w * 16 + kg * 4);
    float inv[4];
#pragma unroll
    for (int r = 0; r < 4; ++r) inv[r] = 1.f / (n4[r] + 1e-6f);
#pragma unroll
    for (int u = 0; u < 4; ++u)
#pragma unroll
      for (int r = 0; r < 4; ++r)
        attn[((long)b * 4096 + nt + w * 16 + kg * 4 + r) * 768 + h * 64 + u * 16 + lr] =
            (_Float16)(oacc[u][r] * inv[r]);
  }
}

// ---------------- launch ----------------

extern "C" void kernel_launch(void* const* d_in, const int* in_sizes, int n_in,
                              void* d_out, int out_size, void* d_ws, size_t ws_size,
                              hipStream_t stream) {
  const float* x = (const float*)d_in[0];
  const float* Wqkv = (const float*)d_in[1];
  const float* Wproj = (const float*)d_in[2];
  const float* bproj = (const float*)d_in[3];
  const float* gamma = (const float*)d_in[4];
  const float* beta = (const float*)d_in[5];
  const float* rfm = (const float*)d_in[6];

  char* ws = (char*)d_ws;
  size_t off = 0;
  auto alloc = [&](size_t bytes) -> void* {
    void* p = ws + off;
    off += (bytes + 255) & ~(size_t)255;
    return p;
  };
  // region A (48MiB), time-shared: x_h -> kvpart -> attn
  char* regionA = (char*)alloc(50331648ULL);
  _Float16* x_h = (_Float16*)regionA;
  _Float16* kvpart = (_Float16*)regionA;  // 96*8*256*64*2 = 25165824 B
  _Float16* attn = (_Float16*)regionA;    // 32768*768*2   = 50331648 B

  _Float16* wqkvT = (_Float16*)alloc(1769472ULL * 2);
  _Float16* wprojT = (_Float16*)alloc(589824ULL * 2);
  _Float16* rfh = (_Float16*)alloc(16384ULL * 2);
  _Float16* qh = (_Float16*)alloc(25165824ULL * 2);   // [bh][n][64]
  _Float16* kh = (_Float16*)alloc(25165824ULL * 2);   // [bh][n][64]
  _Float16* vT = (_Float16*)alloc(25165824ULL * 2);   // [bh][64][n]
  float* nsqLq = (float*)alloc(393216ULL * 4);
  float* nsqLk = (float*)alloc(393216ULL * 4);
  float* kspart = (float*)alloc(96ULL * 8 * 256 * 4);
  _Float16* kvT = (_Float16*)alloc(96ULL * 16384 * 2);  // [bh][d][m]
  _Float16* ksumh = (_Float16*)alloc(96ULL * 256 * 2);
  // total ~207 MB

  float* y = (float*)d_out;

  prep<<<25216, 256, 0, stream>>>(x, Wqkv, Wproj, rfm, x_h, wqkvT, wprojT, rfh);
  gemm_qkv<<<1152, 512, 0, stream>>>(wqkvT, x_h, qh, kh, vT, nsqLq, nsqLk);
  kv_fused<<<dim3(8, 96), 256, 0, stream>>>(kh, vT, rfh, nsqLk, kvpart, kspart);
  reduce_all<<<6240, 256, 0, stream>>>(kvpart, kspart, kvT, ksumh);
  attn_fused<<<dim3(16, 96), 256, 0, stream>>>(qh, rfh, nsqLq, kvT, ksumh, attn);
  proj_ln<<<512, 512, 0, stream>>>(attn, wprojT, bproj, x, gamma, beta, y);
}